// Round 10
// baseline (669.878 us; speedup 1.0000x reference)
//
#include <hip/hip_runtime.h>
#include <math.h>

#define F 64
#define VIOL_THRESH 0.2f
#define BLK_NODES 128
#define H_ROWB 272   // 136 bf16 per row: 68 words ≡ 4 mod 32 banks -> 2-way (free)
#define NSLICE 8     // XCDs on MI355X [measured m09]

typedef float  f32x4  __attribute__((ext_vector_type(4)));
typedef short  bf16x8 __attribute__((ext_vector_type(8)));

__device__ __forceinline__ short f2bf(float f) {
    unsigned u = __builtin_bit_cast(unsigned, f);
    unsigned r = (u + 0x7fffu + ((u >> 16) & 1u)) >> 16;
    return (short)r;
}

__device__ __forceinline__ int get_xcc() {
    int x;
    asm volatile("s_getreg_b32 %0, hwreg(HW_REG_XCC_ID)" : "=s"(x));
    return x & (NSLICE - 1);
}

__global__ void init_minx(int* __restrict__ minx, long total, int n) {
    long i = (long)blockIdx.x * blockDim.x + threadIdx.x;
    if (i < total) minx[i] = n;
}

__global__ void init_min12(int* __restrict__ min1, int* __restrict__ min2, int n) {
    int i = blockIdx.x * blockDim.x + threadIdx.x;
    if (i < n) { min1[i] = n; min2[i] = n; }
}

// fp32 features -> bf16 (one-time pass; node kernel then gathers 128B rows)
__global__ void prep_feat(const float* __restrict__ f, short* __restrict__ fb, long total) {
    long t = (long)blockIdx.x * blockDim.x + threadIdx.x;
    long base = t * 8;
    if (base >= total) return;
    float4 a = *(const float4*)(f + base);
    float4 b = *(const float4*)(f + base + 4);
    bf16x8 o;
    o[0] = f2bf(a.x); o[1] = f2bf(a.y); o[2] = f2bf(a.z); o[3] = f2bf(a.w);
    o[4] = f2bf(b.x); o[5] = f2bf(b.y); o[6] = f2bf(b.z); o[7] = f2bf(b.w);
    *(bf16x8*)(fb + base) = o;
}

// wt1t[o][k]: o in [0,128) (64 rc | 64 cp), k in [0,192)
__global__ void prep_w1(const float* __restrict__ w1rc, const float* __restrict__ w1cp,
                        short* __restrict__ wt1t) {
    int o = blockIdx.x;                      // 0..127
    int k = blockIdx.y * 64 + threadIdx.x;   // 0..191
    const float* src = (o < 64) ? (w1rc + o) : (w1cp + (o - 64));
    wt1t[o * 192 + k] = f2bf(src[(size_t)k * 64]);
}

// wt2t[o][k_perm]: 48 x 128 block-diagonal, k permuted to match packed-H layout:
// k_perm = (k&15)*8 + (k>>4)  (dot over k is permutation-invariant)
__global__ void prep_w2(const float* __restrict__ w2rc, const float* __restrict__ w2cp,
                        short* __restrict__ wt2t) {
    int o = blockIdx.x;                      // 0..47
    int k = blockIdx.y * 64 + threadIdx.x;   // 0..127
    float v = 0.f;
    if (o < 32)       { if (k < 64) v = w2rc[k * 32 + o]; }
    else if (o == 32) { if (k >= 64) v = w2cp[k - 64]; }
    int kp = (k & 15) * 8 + (k >> 4);
    wt2t[o * 128 + kp] = f2bf(v);
}

// ---------------- XCD-local (workgroup-scope) edge passes ----------------
__device__ __forceinline__ void upd1l(int u, int v, int* __restrict__ ms) {
    if (u != v) {
        if (v < ms[u]) __hip_atomic_fetch_min(&ms[u], v, __ATOMIC_RELAXED, __HIP_MEMORY_SCOPE_WORKGROUP);
        if (u < ms[v]) __hip_atomic_fetch_min(&ms[v], u, __ATOMIC_RELAXED, __HIP_MEMORY_SCOPE_WORKGROUP);
    }
}

__global__ void edge_min1_local(const int* __restrict__ e0, const int* __restrict__ e1,
                                int* __restrict__ minx, int m, int n) {
    int* ms = minx + (size_t)get_xcc() * n;
    int t = blockIdx.x * blockDim.x + threadIdx.x;
    int base = t * 4;
    if (base >= m) return;
    if (base + 4 <= m) {
        int4 u4 = *(const int4*)(e0 + base);
        int4 v4 = *(const int4*)(e1 + base);
        upd1l(u4.x, v4.x, ms);
        upd1l(u4.y, v4.y, ms);
        upd1l(u4.z, v4.z, ms);
        upd1l(u4.w, v4.w, ms);
    } else {
        for (int j = base; j < m; j++) upd1l(e0[j], e1[j], ms);
    }
}

__device__ __forceinline__ void upd2l(int u, int v, const int* __restrict__ min1,
                                      int* __restrict__ ms) {
    if (u != v) {
        if (v != min1[u] && v < ms[u]) __hip_atomic_fetch_min(&ms[u], v, __ATOMIC_RELAXED, __HIP_MEMORY_SCOPE_WORKGROUP);
        if (u != min1[v] && u < ms[v]) __hip_atomic_fetch_min(&ms[v], u, __ATOMIC_RELAXED, __HIP_MEMORY_SCOPE_WORKGROUP);
    }
}

__global__ void edge_min2_local(const int* __restrict__ e0, const int* __restrict__ e1,
                                const int* __restrict__ min1, int* __restrict__ minx,
                                int m, int n) {
    int* ms = minx + (size_t)get_xcc() * n;
    int t = blockIdx.x * blockDim.x + threadIdx.x;
    int base = t * 4;
    if (base >= m) return;
    if (base + 4 <= m) {
        int4 u4 = *(const int4*)(e0 + base);
        int4 v4 = *(const int4*)(e1 + base);
        upd2l(u4.x, v4.x, min1, ms);
        upd2l(u4.y, v4.y, min1, ms);
        upd2l(u4.z, v4.z, min1, ms);
        upd2l(u4.w, v4.w, min1, ms);
    } else {
        for (int j = base; j < m; j++) upd2l(e0[j], e1[j], min1, ms);
    }
}

// mout[i] = min over slices; optionally reset slices to sentinel for next pass
__global__ void merge_kernel(int* __restrict__ minx, int* __restrict__ mout,
                             int n, int doreset) {
    int t = blockIdx.x * blockDim.x + threadIdx.x;
    int base = t * 4;
    if (base >= n) return;
    if (base + 4 <= n) {
        int4 mv = *(const int4*)(minx + base);
#pragma unroll
        for (int s = 1; s < NSLICE; s++) {
            int4 o = *(const int4*)(minx + (size_t)s * n + base);
            mv.x = min(mv.x, o.x); mv.y = min(mv.y, o.y);
            mv.z = min(mv.z, o.z); mv.w = min(mv.w, o.w);
        }
        *(int4*)(mout + base) = mv;
        if (doreset) {
            int4 sent; sent.x = n; sent.y = n; sent.z = n; sent.w = n;
#pragma unroll
            for (int s = 0; s < NSLICE; s++)
                *(int4*)(minx + (size_t)s * n + base) = sent;
        }
    } else {
        for (int i = base; i < n; i++) {
            int mv = minx[i];
#pragma unroll
            for (int s = 1; s < NSLICE; s++) mv = min(mv, minx[(size_t)s * n + i]);
            mout[i] = mv;
            if (doreset) {
#pragma unroll
                for (int s = 0; s < NSLICE; s++) minx[(size_t)s * n + i] = n;
            }
        }
    }
}

// ---------------- device-scope fallback (if ws too small for slices) ----------------
__device__ __forceinline__ void upd_min1(int u, int v, int* __restrict__ min1) {
    if (u != v) {
        if (v < min1[u]) atomicMin(&min1[u], v);
        if (u < min1[v]) atomicMin(&min1[v], u);
    }
}

__global__ void edge_min1_kernel(const int* __restrict__ e0, const int* __restrict__ e1,
                                 int* __restrict__ min1, int m) {
    int t = blockIdx.x * blockDim.x + threadIdx.x;
    int base = t * 4;
    if (base >= m) return;
    if (base + 4 <= m) {
        int4 u4 = *(const int4*)(e0 + base);
        int4 v4 = *(const int4*)(e1 + base);
        upd_min1(u4.x, v4.x, min1);
        upd_min1(u4.y, v4.y, min1);
        upd_min1(u4.z, v4.z, min1);
        upd_min1(u4.w, v4.w, min1);
    } else {
        for (int j = base; j < m; j++) upd_min1(e0[j], e1[j], min1);
    }
}

__device__ __forceinline__ void upd_min2(int u, int v, const int* __restrict__ min1,
                                         int* __restrict__ min2) {
    if (u != v) {
        if (v != min1[u] && v < min2[u]) atomicMin(&min2[u], v);
        if (u != min1[v] && u < min2[v]) atomicMin(&min2[v], u);
    }
}

__global__ void edge_min2_kernel(const int* __restrict__ e0, const int* __restrict__ e1,
                                 const int* __restrict__ min1, int* __restrict__ min2, int m) {
    int t = blockIdx.x * blockDim.x + threadIdx.x;
    int base = t * 4;
    if (base >= m) return;
    if (base + 4 <= m) {
        int4 u4 = *(const int4*)(e0 + base);
        int4 v4 = *(const int4*)(e1 + base);
        upd_min2(u4.x, v4.x, min1, min2);
        upd_min2(u4.y, v4.y, min1, min2);
        upd_min2(u4.z, v4.z, min1, min2);
        upd_min2(u4.w, v4.w, min1, min2);
    } else {
        for (int j = base; j < m; j++) upd_min2(e0[j], e1[j], min1, min2);
    }
}

template<bool BF>
__global__ __launch_bounds__(256)
void node_kernel(const float* __restrict__ feat, const short* __restrict__ featbf,
                 const float* __restrict__ radii,
                 const float* __restrict__ b1rc, const float* __restrict__ b2rc,
                 const float* __restrict__ w3rc, const float* __restrict__ b3rc,
                 const float* __restrict__ b1cp, const float* __restrict__ b2cp,
                 const short* __restrict__ wt1t, const short* __restrict__ wt2t,
                 const int* __restrict__ types,
                 const int* __restrict__ min1, const int* __restrict__ min2,
                 float* __restrict__ gates, float4* __restrict__ partials,
                 int n) {
    // NOTE: no __syncthreads in this kernel. Each wave touches ONLY its own
    // 32-node slice of Hbuf/corrArr/zArr; within-wave DS ordering is
    // guaranteed by the in-order LDS pipe + compiler lgkmcnt waits.
    __shared__ __align__(16) char Hbuf[BLK_NODES * H_ROWB];   // 34816 B
    __shared__ float corrArr[BLK_NODES];
    __shared__ float zArr[BLK_NODES];

    int tid = threadIdx.x;
    int blk = blockIdx.x;
    int lane = tid & 63;
    int w = tid >> 6;
    int lm = lane & 15;
    int lg = lane >> 4;
    int wnb = w * 32;

    // node ids per (m-tile, part)
    int nid[2][3];
#pragma unroll
    for (int mt = 0; mt < 2; mt++) {
        int g = blk * BLK_NODES + wnb + mt * 16 + lm;
        int ii = (g < n) ? g : (n - 1);
        int m1 = min1[ii];
        int m2 = min2[ii];
        nid[mt][0] = ii;
        nid[mt][1] = (m1 < n) ? m1 : (n - 1);
        nid[mt][2] = (m2 < n) ? m2 : (n - 1);
    }

    // ---------- prefetch ALL layer-1 A-fragments (12 x 16B, all in flight) ----------
    bf16x8 af[2][3][2];
    if constexpr (BF) {
#pragma unroll
        for (int mt = 0; mt < 2; mt++)
#pragma unroll
            for (int part = 0; part < 3; part++)
#pragma unroll
                for (int h = 0; h < 2; h++)
                    af[mt][part][h] = *(const bf16x8*)(featbf + (size_t)nid[mt][part] * F + h * 32 + lg * 8);
    }

    // ---------- layer 1: H[32 nodes][128 outs] per wave ----------
    f32x4 zero4 = {0.f, 0.f, 0.f, 0.f};
    f32x4 acc[2][8];
#pragma unroll
    for (int mt = 0; mt < 2; mt++)
#pragma unroll
        for (int nt = 0; nt < 8; nt++) acc[mt][nt] = zero4;

#pragma unroll
    for (int s = 0; s < 6; s++) {
        int part = s >> 1;
        int h = s & 1;
        bf16x8 a0, a1;
        if constexpr (BF) {
            a0 = af[0][part][h];
            a1 = af[1][part][h];
        } else {
#pragma unroll
            for (int mt = 0; mt < 2; mt++) {
                const float* rp = feat + (size_t)nid[mt][part] * F + h * 32 + lg * 8;
                float4 f0 = *(const float4*)rp;
                float4 f1 = *(const float4*)(rp + 4);
                bf16x8 a;
                a[0] = f2bf(f0.x); a[1] = f2bf(f0.y); a[2] = f2bf(f0.z); a[3] = f2bf(f0.w);
                a[4] = f2bf(f1.x); a[5] = f2bf(f1.y); a[6] = f2bf(f1.z); a[7] = f2bf(f1.w);
                if (mt == 0) a0 = a; else a1 = a;
            }
        }
#pragma unroll
        for (int nt = 0; nt < 8; nt++) {
            bf16x8 b = *(const bf16x8*)(wt1t + (lm + 16 * nt) * 192 + s * 32 + lg * 8);
            acc[0][nt] = __builtin_amdgcn_mfma_f32_16x16x32_bf16(a0, b, acc[0][nt], 0, 0, 0);
            acc[1][nt] = __builtin_amdgcn_mfma_f32_16x16x32_bf16(a1, b, acc[1][nt], 0, 0, 0);
        }
    }

    // biases for this lane's 8 output columns (o = lm + 16*nt)
    float b1v[8];
#pragma unroll
    for (int nt = 0; nt < 8; nt++)
        b1v[nt] = (nt < 4) ? b1rc[lm + 16 * nt] : b1cp[lm + 16 * nt - 64];

    // packed H store: row layout o_perm = lm*8 + nt  -> one ds_write_b128 per (mt,r)
#pragma unroll
    for (int mt = 0; mt < 2; mt++) {
#pragma unroll
        for (int r = 0; r < 4; r++) {
            int node = wnb + mt * 16 + lg * 4 + r;
            bf16x8 hv;
#pragma unroll
            for (int nt = 0; nt < 8; nt++)
                hv[nt] = f2bf(fmaxf(acc[mt][nt][r] + b1v[nt], 0.f));
            *(bf16x8*)(Hbuf + node * H_ROWB + lm * 16) = hv;
        }
    }

    // ---------- layer 2: [32 nodes][33 of 48] (k in permuted order both sides) ----------
    f32x4 acc2[2][3];
#pragma unroll
    for (int mt = 0; mt < 2; mt++)
#pragma unroll
        for (int nt = 0; nt < 3; nt++) acc2[mt][nt] = zero4;

#pragma unroll
    for (int s = 0; s < 4; s++) {
        bf16x8 af2[2];
#pragma unroll
        for (int mt = 0; mt < 2; mt++)
            af2[mt] = *(const bf16x8*)(Hbuf + (wnb + mt * 16 + lm) * H_ROWB + s * 64 + lg * 16);
#pragma unroll
        for (int nt = 0; nt < 3; nt++) {
            bf16x8 b = *(const bf16x8*)(wt2t + (lm + 16 * nt) * 128 + s * 32 + lg * 8);
            acc2[0][nt] = __builtin_amdgcn_mfma_f32_16x16x32_bf16(af2[0], b, acc2[0][nt], 0, 0, 0);
            acc2[1][nt] = __builtin_amdgcn_mfma_f32_16x16x32_bf16(af2[1], b, acc2[1][nt], 0, 0, 0);
        }
    }

    // corr / z per node (within-wave shfl reduce, stash in wave's LDS slice)
#pragma unroll
    for (int mt = 0; mt < 2; mt++) {
#pragma unroll
        for (int r = 0; r < 4; r++) {
            float t = 0.f;
#pragma unroll
            for (int nt = 0; nt < 2; nt++) {
                int o = lm + 16 * nt;
                float s2v = fmaxf(acc2[mt][nt][r] + b2rc[o], 0.f);
                t = fmaf(s2v, w3rc[o], t);
            }
            float zz = acc2[mt][2][r];   // only o==32 (lm==0) nonzero; rest exact zeros
#pragma unroll
            for (int msk = 1; msk < 16; msk <<= 1) {
                t  += __shfl_xor(t, msk);
                zz += __shfl_xor(zz, msk);
            }
            if (lm == 0) {
                int node = wnb + mt * 16 + lg * 4 + r;
                corrArr[node] = t + b3rc[0];
                zArr[node]    = zz + b2cp[0];
            }
        }
    }

    // ---------- per-wave epilogue: lanes 0..31 handle the wave's 32 nodes ----------
    float sv = 0.f, sc = 0.f, ct = 0.f;
    if (lane < 32) {
        int loc = wnb + lane;
        int g = blk * BLK_NODES + loc;
        bool live = g < n;
        int ii = live ? g : (n - 1);
        int m1 = min1[ii];
        int m2 = min2[ii];
        bool valid = m2 < n;
        int c1 = (m1 < n) ? m1 : (n - 1);
        int c2 = (m2 < n) ? m2 : (n - 1);
        float rp_ = radii[ii], r1_ = radii[c1], r2_ = radii[c2];
        float pr3 = rp_ * rp_ * rp_;
        float viol = fabsf(r1_ * r1_ * r1_ + r2_ * r2_ * r2_ - pr3) / pr3;
        bool active = live && valid && (types[ii] == 1);
        bool upd = active && (viol > VIOL_THRESH);
        float gate = upd ? corrArr[loc] : 0.f;
        if (live) gates[g] = 0.1f * gate;
        if (active) {
            sv = viol;
            sc = 1.0f / (1.0f + expf(-zArr[loc]));
            ct = 1.f;
        }
    }
#pragma unroll
    for (int off = 32; off > 0; off >>= 1) {
        sv += __shfl_down(sv, off);
        sc += __shfl_down(sc, off);
        ct += __shfl_down(ct, off);
    }
    if (lane == 0) {
        float4 p; p.x = sv; p.y = sc; p.z = ct; p.w = 0.f;
        partials[blk * 4 + w] = p;
    }
}

// pure streaming: out = feat + gates[node] * tanh(feat)
__global__ __launch_bounds__(256)
void update_kernel(const float* __restrict__ feat, const float* __restrict__ gates,
                   float* __restrict__ out, long total4) {
    long stride = (long)gridDim.x * blockDim.x;
    for (long t = (long)blockIdx.x * blockDim.x + threadIdx.x; t < total4; t += stride) {
        long base = t * 4;
        int node = (int)(base >> 6);          // F=64 floats per node
        float g = gates[node];
        float4 v = *(const float4*)(feat + base);
        float4 r;
        r.x = v.x + g * tanhf(v.x);
        r.y = v.y + g * tanhf(v.y);
        r.z = v.z + g * tanhf(v.z);
        r.w = v.w + g * tanhf(v.w);
        *(float4*)(out + base) = r;
    }
}

__global__ __launch_bounds__(256)
void finalize_kernel(const float4* __restrict__ partials, int np,
                     float* __restrict__ out_scalars) {
    __shared__ float red[3][4];
    int tid = threadIdx.x;
    float sv = 0.f, sc = 0.f, ct = 0.f;
    for (int i = tid; i < np; i += 256) {
        float4 p = partials[i];
        sv += p.x; sc += p.y; ct += p.z;
    }
#pragma unroll
    for (int off = 32; off > 0; off >>= 1) {
        sv += __shfl_down(sv, off);
        sc += __shfl_down(sc, off);
        ct += __shfl_down(ct, off);
    }
    int lane = tid & 63, w = tid >> 6;
    if (lane == 0) { red[0][w] = sv; red[1][w] = sc; red[2][w] = ct; }
    __syncthreads();
    if (tid == 0) {
        float tv = red[0][0] + red[0][1] + red[0][2] + red[0][3];
        float tc = red[1][0] + red[1][1] + red[1][2] + red[1][3];
        float tn = red[2][0] + red[2][1] + red[2][2] + red[2][3];
        float d = tn > 1.f ? tn : 1.f;
        out_scalars[0] = tv / d;
        out_scalars[1] = tc / d;
    }
}

extern "C" void kernel_launch(void* const* d_in, const int* in_sizes, int n_in,
                              void* d_out, int out_size, void* d_ws, size_t ws_size,
                              hipStream_t stream) {
    const float* feat  = (const float*)d_in[0];
    const float* radii = (const float*)d_in[1];
    const float* w1rc  = (const float*)d_in[2];
    const float* b1rc  = (const float*)d_in[3];
    const float* w2rc  = (const float*)d_in[4];
    const float* b2rc  = (const float*)d_in[5];
    const float* w3rc  = (const float*)d_in[6];
    const float* b3rc  = (const float*)d_in[7];
    const float* w1cp  = (const float*)d_in[8];
    const float* b1cp  = (const float*)d_in[9];
    const float* w2cp  = (const float*)d_in[10];
    const float* b2cp  = (const float*)d_in[11];
    const int*   eidx  = (const int*)d_in[12];
    const int*   types = (const int*)d_in[13];

    int n = in_sizes[0] / F;          // 300000
    int m = in_sizes[12] / 2;         // 3000000

    int nblocks = (n + BLK_NODES - 1) / BLK_NODES;
    int np = nblocks * 4;

    // ws layout: wt1t | wt2t | min1 | min2 | partials | gates | minx(8n) | featbf
    char* ws = (char*)d_ws;
    short* wt1t = (short*)ws;                            ws += 128 * 192 * 2;
    short* wt2t = (short*)ws;                            ws += 48 * 128 * 2;
    int* min1 = (int*)ws;                                ws += (size_t)n * 4;
    int* min2 = (int*)ws;                                ws += (size_t)n * 4;
    float4* partials = (float4*)ws;                      ws += (size_t)np * 16;
    float* gates = (float*)ws;                           ws += (size_t)n * 4;
    int* minx = (int*)ws;
    size_t minx_bytes = (size_t)NSLICE * n * 4;
    bool useLocal = ((size_t)(ws - (char*)d_ws) + minx_bytes) <= ws_size;
    if (useLocal) ws += minx_bytes;
    short* featbf = (short*)ws;
    size_t featbf_bytes = (size_t)n * F * 2;
    bool useBF = ((size_t)(ws - (char*)d_ws) + featbf_bytes) <= ws_size;

    float* out         = (float*)d_out;
    float* out_scalars = out + (size_t)n * F;

    int bs = 256;
    if (useBF) {
        long total = (long)n * F;
        long nthr = total / 8;
        prep_feat<<<(unsigned)((nthr + bs - 1) / bs), bs, 0, stream>>>(feat, featbf, total);
    }
    prep_w1<<<dim3(128, 3), 64, 0, stream>>>(w1rc, w1cp, wt1t);
    prep_w2<<<dim3(48, 2), 64, 0, stream>>>(w2rc, w2cp, wt2t);

    int mt4 = (m + 3) / 4;
    int n4  = (n + 3) / 4;
    if (useLocal) {
        long total = (long)NSLICE * n;
        init_minx<<<(unsigned)((total + bs - 1) / bs), bs, 0, stream>>>(minx, total, n);
        edge_min1_local<<<(mt4 + bs - 1) / bs, bs, 0, stream>>>(eidx, eidx + m, minx, m, n);
        merge_kernel<<<(n4 + bs - 1) / bs, bs, 0, stream>>>(minx, min1, n, 1);
        edge_min2_local<<<(mt4 + bs - 1) / bs, bs, 0, stream>>>(eidx, eidx + m, min1, minx, m, n);
        merge_kernel<<<(n4 + bs - 1) / bs, bs, 0, stream>>>(minx, min2, n, 0);
    } else {
        init_min12<<<(n + bs - 1) / bs, bs, 0, stream>>>(min1, min2, n);
        edge_min1_kernel<<<(mt4 + bs - 1) / bs, bs, 0, stream>>>(eidx, eidx + m, min1, m);
        edge_min2_kernel<<<(mt4 + bs - 1) / bs, bs, 0, stream>>>(eidx, eidx + m, min1, min2, m);
    }

    if (useBF) {
        node_kernel<true><<<nblocks, bs, 0, stream>>>(
            feat, featbf, radii, b1rc, b2rc, w3rc, b3rc, b1cp, b2cp,
            wt1t, wt2t, types, min1, min2, gates, partials, n);
    } else {
        node_kernel<false><<<nblocks, bs, 0, stream>>>(
            feat, featbf, radii, b1rc, b2rc, w3rc, b3rc, b1cp, b2cp,
            wt1t, wt2t, types, min1, min2, gates, partials, n);
    }
    long total4 = (long)n * F / 4;
    update_kernel<<<2048, bs, 0, stream>>>(feat, gates, out, total4);
    finalize_kernel<<<1, 256, 0, stream>>>(partials, np, out_scalars);
}

// Round 11
// 316.320 us; speedup vs baseline: 2.1177x; 2.1177x over previous
//
#include <hip/hip_runtime.h>
#include <math.h>

#define F 64
#define VIOL_THRESH 0.2f
#define BLK_NODES 128
#define H_ROWB 272   // 136 bf16 per row: 68 words ≡ 4 mod 32 banks -> 2-way (free)
#define BIN_SHIFT 11
#define BIN_SIZE 2048
#define NBIN_PAD 256
#define TILE 2048

typedef float  f32x4  __attribute__((ext_vector_type(4)));
typedef short  bf16x8 __attribute__((ext_vector_type(8)));

__device__ __forceinline__ short f2bf(float f) {
    unsigned u = __builtin_bit_cast(unsigned, f);
    unsigned r = (u + 0x7fffu + ((u >> 16) & 1u)) >> 16;
    return (short)r;
}

// ---------------- binned two-smallest-neighbor pipeline ----------------

__global__ void zero_counts(int* __restrict__ counts) {
    counts[threadIdx.x] = 0;
}

__global__ __launch_bounds__(256)
void count_kernel(const int* __restrict__ e0, const int* __restrict__ e1,
                  int* __restrict__ counts, int m) {
    __shared__ int c[NBIN_PAD];
    int tid = threadIdx.x;
    c[tid] = 0;
    __syncthreads();
    for (long j = (long)blockIdx.x * 256 + tid; j < m; j += (long)gridDim.x * 256) {
        int u = e0[j], v = e1[j];
        if (u != v) {
            atomicAdd(&c[u >> BIN_SHIFT], 1);
            atomicAdd(&c[v >> BIN_SHIFT], 1);
        }
    }
    __syncthreads();
    if (c[tid]) atomicAdd(&counts[tid], c[tid]);
}

__global__ void scan_kernel(const int* __restrict__ counts,
                            int* __restrict__ offsets, int* __restrict__ cursors) {
    __shared__ int tmp[NBIN_PAD];
    __shared__ int cnt[NBIN_PAD];
    int tid = threadIdx.x;
    cnt[tid] = counts[tid];
    tmp[tid] = cnt[tid];
    __syncthreads();
    for (int off = 1; off < NBIN_PAD; off <<= 1) {
        int v = (tid >= off) ? tmp[tid - off] : 0;
        __syncthreads();
        tmp[tid] += v;
        __syncthreads();
    }
    int excl = tmp[tid] - cnt[tid];
    offsets[tid] = excl;
    cursors[tid] = excl;
    if (tid == NBIN_PAD - 1) offsets[NBIN_PAD] = tmp[NBIN_PAD - 1];
}

__global__ __launch_bounds__(256)
void scatter_kernel(const int* __restrict__ e0, const int* __restrict__ e1,
                    int* __restrict__ cursors, unsigned* __restrict__ binned, int m) {
    __shared__ unsigned long long buf[2 * TILE];          // 32 KB
    __shared__ int tcount[NBIN_PAD], toff[NBIN_PAD], tmp[NBIN_PAD];
    __shared__ int gbase[NBIN_PAD], tcur[NBIN_PAD];
    __shared__ int totalsh;
    int tid = threadIdx.x;
    int ntile = (m + TILE - 1) / TILE;
    for (int tile = blockIdx.x; tile < ntile; tile += gridDim.x) {
        int base = tile * TILE;
        int lim = min(TILE, m - base);
        tcount[tid] = 0;
        __syncthreads();
        for (int j = tid; j < lim; j += 256) {
            int u = e0[base + j], v = e1[base + j];
            if (u != v) {
                atomicAdd(&tcount[u >> BIN_SHIFT], 1);
                atomicAdd(&tcount[v >> BIN_SHIFT], 1);
            }
        }
        __syncthreads();
        tmp[tid] = tcount[tid];
        __syncthreads();
        for (int off = 1; off < NBIN_PAD; off <<= 1) {
            int vv = (tid >= off) ? tmp[tid - off] : 0;
            __syncthreads();
            tmp[tid] += vv;
            __syncthreads();
        }
        toff[tid] = tmp[tid] - tcount[tid];
        if (tid == NBIN_PAD - 1) totalsh = tmp[NBIN_PAD - 1];
        {
            int cct = tcount[tid];
            gbase[tid] = cct ? atomicAdd(&cursors[tid], cct) : 0;
            tcur[tid] = tmp[tid] - cct;
        }
        __syncthreads();
        for (int j = tid; j < lim; j += 256) {
            int u = e0[base + j], v = e1[base + j];
            if (u != v) {
                int b1 = u >> BIN_SHIFT;
                int s1 = atomicAdd(&tcur[b1], 1);
                buf[s1] = ((unsigned long long)b1 << 32) |
                          (unsigned)(((u & (BIN_SIZE - 1)) << 19) | v);
                int b2 = v >> BIN_SHIFT;
                int s2 = atomicAdd(&tcur[b2], 1);
                buf[s2] = ((unsigned long long)b2 << 32) |
                          (unsigned)(((v & (BIN_SIZE - 1)) << 19) | u);
            }
        }
        __syncthreads();
        int total = totalsh;
        for (int t = tid; t < total; t += 256) {
            unsigned long long e = buf[t];
            int b = (int)(e >> 32);
            binned[gbase[b] + (t - toff[b])] = (unsigned)e;
        }
        __syncthreads();
    }
}

__global__ __launch_bounds__(256)
void process_kernel(const unsigned* __restrict__ binned, const int* __restrict__ offsets,
                    int* __restrict__ min1, int* __restrict__ min2, int n) {
    __shared__ int m1s[BIN_SIZE], m2s[BIN_SIZE];   // 16 KB
    int tid = threadIdx.x, b = blockIdx.x;
    for (int i = tid; i < BIN_SIZE; i += 256) { m1s[i] = n; m2s[i] = n; }
    __syncthreads();
    int s = offsets[b], e = offsets[b + 1];
    for (int j = s + tid; j < e; j += 256) {
        unsigned p = binned[j];
        atomicMin(&m1s[p >> 19], (int)(p & 0x7FFFFu));
    }
    __syncthreads();
    for (int j = s + tid; j < e; j += 256) {
        unsigned p = binned[j];
        int lu = p >> 19, v = (int)(p & 0x7FFFFu);
        if (v != m1s[lu]) atomicMin(&m2s[lu], v);
    }
    __syncthreads();
    int gb = b << BIN_SHIFT;
    for (int i = tid; i < BIN_SIZE; i += 256) {
        int g = gb + i;
        if (g < n) { min1[g] = m1s[i]; min2[g] = m2s[i]; }
    }
}

// ---------------- device-scope fallback (n too large or ws too small) ----------------
__global__ void init_min12(int* __restrict__ min1, int* __restrict__ min2, int n) {
    int i = blockIdx.x * blockDim.x + threadIdx.x;
    if (i < n) { min1[i] = n; min2[i] = n; }
}

__device__ __forceinline__ void upd_min1(int u, int v, int* __restrict__ min1) {
    if (u != v) {
        if (v < min1[u]) atomicMin(&min1[u], v);
        if (u < min1[v]) atomicMin(&min1[v], u);
    }
}

__global__ void edge_min1_kernel(const int* __restrict__ e0, const int* __restrict__ e1,
                                 int* __restrict__ min1, int m) {
    int t = blockIdx.x * blockDim.x + threadIdx.x;
    int base = t * 4;
    if (base >= m) return;
    if (base + 4 <= m) {
        int4 u4 = *(const int4*)(e0 + base);
        int4 v4 = *(const int4*)(e1 + base);
        upd_min1(u4.x, v4.x, min1);
        upd_min1(u4.y, v4.y, min1);
        upd_min1(u4.z, v4.z, min1);
        upd_min1(u4.w, v4.w, min1);
    } else {
        for (int j = base; j < m; j++) upd_min1(e0[j], e1[j], min1);
    }
}

__device__ __forceinline__ void upd_min2(int u, int v, const int* __restrict__ min1,
                                         int* __restrict__ min2) {
    if (u != v) {
        if (v != min1[u] && v < min2[u]) atomicMin(&min2[u], v);
        if (u != min1[v] && u < min2[v]) atomicMin(&min2[v], u);
    }
}

__global__ void edge_min2_kernel(const int* __restrict__ e0, const int* __restrict__ e1,
                                 const int* __restrict__ min1, int* __restrict__ min2, int m) {
    int t = blockIdx.x * blockDim.x + threadIdx.x;
    int base = t * 4;
    if (base >= m) return;
    if (base + 4 <= m) {
        int4 u4 = *(const int4*)(e0 + base);
        int4 v4 = *(const int4*)(e1 + base);
        upd_min2(u4.x, v4.x, min1, min2);
        upd_min2(u4.y, v4.y, min1, min2);
        upd_min2(u4.z, v4.z, min1, min2);
        upd_min2(u4.w, v4.w, min1, min2);
    } else {
        for (int j = base; j < m; j++) upd_min2(e0[j], e1[j], min1, min2);
    }
}

// ---------------- prep kernels ----------------
__global__ void prep_feat(const float* __restrict__ f, short* __restrict__ fb, long total) {
    long t = (long)blockIdx.x * blockDim.x + threadIdx.x;
    long base = t * 8;
    if (base >= total) return;
    float4 a = *(const float4*)(f + base);
    float4 b = *(const float4*)(f + base + 4);
    bf16x8 o;
    o[0] = f2bf(a.x); o[1] = f2bf(a.y); o[2] = f2bf(a.z); o[3] = f2bf(a.w);
    o[4] = f2bf(b.x); o[5] = f2bf(b.y); o[6] = f2bf(b.z); o[7] = f2bf(b.w);
    *(bf16x8*)(fb + base) = o;
}

__global__ void prep_w1(const float* __restrict__ w1rc, const float* __restrict__ w1cp,
                        short* __restrict__ wt1t) {
    int o = blockIdx.x;
    int k = blockIdx.y * 64 + threadIdx.x;
    const float* src = (o < 64) ? (w1rc + o) : (w1cp + (o - 64));
    wt1t[o * 192 + k] = f2bf(src[(size_t)k * 64]);
}

__global__ void prep_w2(const float* __restrict__ w2rc, const float* __restrict__ w2cp,
                        short* __restrict__ wt2t) {
    int o = blockIdx.x;
    int k = blockIdx.y * 64 + threadIdx.x;
    float v = 0.f;
    if (o < 32)       { if (k < 64) v = w2rc[k * 32 + o]; }
    else if (o == 32) { if (k >= 64) v = w2cp[k - 64]; }
    int kp = (k & 15) * 8 + (k >> 4);
    wt2t[o * 128 + kp] = f2bf(v);
}

// ---------------- node / update / finalize (unchanged) ----------------
template<bool BF>
__global__ __launch_bounds__(256)
void node_kernel(const float* __restrict__ feat, const short* __restrict__ featbf,
                 const float* __restrict__ radii,
                 const float* __restrict__ b1rc, const float* __restrict__ b2rc,
                 const float* __restrict__ w3rc, const float* __restrict__ b3rc,
                 const float* __restrict__ b1cp, const float* __restrict__ b2cp,
                 const short* __restrict__ wt1t, const short* __restrict__ wt2t,
                 const int* __restrict__ types,
                 const int* __restrict__ min1, const int* __restrict__ min2,
                 float* __restrict__ gates, float4* __restrict__ partials,
                 int n) {
    __shared__ __align__(16) char Hbuf[BLK_NODES * H_ROWB];
    __shared__ float corrArr[BLK_NODES];
    __shared__ float zArr[BLK_NODES];

    int tid = threadIdx.x;
    int blk = blockIdx.x;
    int lane = tid & 63;
    int w = tid >> 6;
    int lm = lane & 15;
    int lg = lane >> 4;
    int wnb = w * 32;

    int nid[2][3];
#pragma unroll
    for (int mt = 0; mt < 2; mt++) {
        int g = blk * BLK_NODES + wnb + mt * 16 + lm;
        int ii = (g < n) ? g : (n - 1);
        int m1 = min1[ii];
        int m2 = min2[ii];
        nid[mt][0] = ii;
        nid[mt][1] = (m1 < n) ? m1 : (n - 1);
        nid[mt][2] = (m2 < n) ? m2 : (n - 1);
    }

    bf16x8 af[2][3][2];
    if constexpr (BF) {
#pragma unroll
        for (int mt = 0; mt < 2; mt++)
#pragma unroll
            for (int part = 0; part < 3; part++)
#pragma unroll
                for (int h = 0; h < 2; h++)
                    af[mt][part][h] = *(const bf16x8*)(featbf + (size_t)nid[mt][part] * F + h * 32 + lg * 8);
    }

    f32x4 zero4 = {0.f, 0.f, 0.f, 0.f};
    f32x4 acc[2][8];
#pragma unroll
    for (int mt = 0; mt < 2; mt++)
#pragma unroll
        for (int nt = 0; nt < 8; nt++) acc[mt][nt] = zero4;

#pragma unroll
    for (int s = 0; s < 6; s++) {
        int part = s >> 1;
        int h = s & 1;
        bf16x8 a0, a1;
        if constexpr (BF) {
            a0 = af[0][part][h];
            a1 = af[1][part][h];
        } else {
#pragma unroll
            for (int mt = 0; mt < 2; mt++) {
                const float* rp = feat + (size_t)nid[mt][part] * F + h * 32 + lg * 8;
                float4 f0 = *(const float4*)rp;
                float4 f1 = *(const float4*)(rp + 4);
                bf16x8 a;
                a[0] = f2bf(f0.x); a[1] = f2bf(f0.y); a[2] = f2bf(f0.z); a[3] = f2bf(f0.w);
                a[4] = f2bf(f1.x); a[5] = f2bf(f1.y); a[6] = f2bf(f1.z); a[7] = f2bf(f1.w);
                if (mt == 0) a0 = a; else a1 = a;
            }
        }
#pragma unroll
        for (int nt = 0; nt < 8; nt++) {
            bf16x8 b = *(const bf16x8*)(wt1t + (lm + 16 * nt) * 192 + s * 32 + lg * 8);
            acc[0][nt] = __builtin_amdgcn_mfma_f32_16x16x32_bf16(a0, b, acc[0][nt], 0, 0, 0);
            acc[1][nt] = __builtin_amdgcn_mfma_f32_16x16x32_bf16(a1, b, acc[1][nt], 0, 0, 0);
        }
    }

    float b1v[8];
#pragma unroll
    for (int nt = 0; nt < 8; nt++)
        b1v[nt] = (nt < 4) ? b1rc[lm + 16 * nt] : b1cp[lm + 16 * nt - 64];

#pragma unroll
    for (int mt = 0; mt < 2; mt++) {
#pragma unroll
        for (int r = 0; r < 4; r++) {
            int node = wnb + mt * 16 + lg * 4 + r;
            bf16x8 hv;
#pragma unroll
            for (int nt = 0; nt < 8; nt++)
                hv[nt] = f2bf(fmaxf(acc[mt][nt][r] + b1v[nt], 0.f));
            *(bf16x8*)(Hbuf + node * H_ROWB + lm * 16) = hv;
        }
    }

    f32x4 acc2[2][3];
#pragma unroll
    for (int mt = 0; mt < 2; mt++)
#pragma unroll
        for (int nt = 0; nt < 3; nt++) acc2[mt][nt] = zero4;

#pragma unroll
    for (int s = 0; s < 4; s++) {
        bf16x8 af2[2];
#pragma unroll
        for (int mt = 0; mt < 2; mt++)
            af2[mt] = *(const bf16x8*)(Hbuf + (wnb + mt * 16 + lm) * H_ROWB + s * 64 + lg * 16);
#pragma unroll
        for (int nt = 0; nt < 3; nt++) {
            bf16x8 b = *(const bf16x8*)(wt2t + (lm + 16 * nt) * 128 + s * 32 + lg * 8);
            acc2[0][nt] = __builtin_amdgcn_mfma_f32_16x16x32_bf16(af2[0], b, acc2[0][nt], 0, 0, 0);
            acc2[1][nt] = __builtin_amdgcn_mfma_f32_16x16x32_bf16(af2[1], b, acc2[1][nt], 0, 0, 0);
        }
    }

#pragma unroll
    for (int mt = 0; mt < 2; mt++) {
#pragma unroll
        for (int r = 0; r < 4; r++) {
            float t = 0.f;
#pragma unroll
            for (int nt = 0; nt < 2; nt++) {
                int o = lm + 16 * nt;
                float s2v = fmaxf(acc2[mt][nt][r] + b2rc[o], 0.f);
                t = fmaf(s2v, w3rc[o], t);
            }
            float zz = acc2[mt][2][r];
#pragma unroll
            for (int msk = 1; msk < 16; msk <<= 1) {
                t  += __shfl_xor(t, msk);
                zz += __shfl_xor(zz, msk);
            }
            if (lm == 0) {
                int node = wnb + mt * 16 + lg * 4 + r;
                corrArr[node] = t + b3rc[0];
                zArr[node]    = zz + b2cp[0];
            }
        }
    }

    float sv = 0.f, sc = 0.f, ct = 0.f;
    if (lane < 32) {
        int loc = wnb + lane;
        int g = blk * BLK_NODES + loc;
        bool live = g < n;
        int ii = live ? g : (n - 1);
        int m1 = min1[ii];
        int m2 = min2[ii];
        bool valid = m2 < n;
        int c1 = (m1 < n) ? m1 : (n - 1);
        int c2 = (m2 < n) ? m2 : (n - 1);
        float rp_ = radii[ii], r1_ = radii[c1], r2_ = radii[c2];
        float pr3 = rp_ * rp_ * rp_;
        float viol = fabsf(r1_ * r1_ * r1_ + r2_ * r2_ * r2_ - pr3) / pr3;
        bool active = live && valid && (types[ii] == 1);
        bool upd = active && (viol > VIOL_THRESH);
        float gate = upd ? corrArr[loc] : 0.f;
        if (live) gates[g] = 0.1f * gate;
        if (active) {
            sv = viol;
            sc = 1.0f / (1.0f + expf(-zArr[loc]));
            ct = 1.f;
        }
    }
#pragma unroll
    for (int off = 32; off > 0; off >>= 1) {
        sv += __shfl_down(sv, off);
        sc += __shfl_down(sc, off);
        ct += __shfl_down(ct, off);
    }
    if (lane == 0) {
        float4 p; p.x = sv; p.y = sc; p.z = ct; p.w = 0.f;
        partials[blk * 4 + w] = p;
    }
}

__global__ __launch_bounds__(256)
void update_kernel(const float* __restrict__ feat, const float* __restrict__ gates,
                   float* __restrict__ out, long total4) {
    long stride = (long)gridDim.x * blockDim.x;
    for (long t = (long)blockIdx.x * blockDim.x + threadIdx.x; t < total4; t += stride) {
        long base = t * 4;
        int node = (int)(base >> 6);
        float g = gates[node];
        float4 v = *(const float4*)(feat + base);
        float4 r;
        r.x = v.x + g * tanhf(v.x);
        r.y = v.y + g * tanhf(v.y);
        r.z = v.z + g * tanhf(v.z);
        r.w = v.w + g * tanhf(v.w);
        *(float4*)(out + base) = r;
    }
}

__global__ __launch_bounds__(256)
void finalize_kernel(const float4* __restrict__ partials, int np,
                     float* __restrict__ out_scalars) {
    __shared__ float red[3][4];
    int tid = threadIdx.x;
    float sv = 0.f, sc = 0.f, ct = 0.f;
    for (int i = tid; i < np; i += 256) {
        float4 p = partials[i];
        sv += p.x; sc += p.y; ct += p.z;
    }
#pragma unroll
    for (int off = 32; off > 0; off >>= 1) {
        sv += __shfl_down(sv, off);
        sc += __shfl_down(sc, off);
        ct += __shfl_down(ct, off);
    }
    int lane = tid & 63, w = tid >> 6;
    if (lane == 0) { red[0][w] = sv; red[1][w] = sc; red[2][w] = ct; }
    __syncthreads();
    if (tid == 0) {
        float tv = red[0][0] + red[0][1] + red[0][2] + red[0][3];
        float tc = red[1][0] + red[1][1] + red[1][2] + red[1][3];
        float tn = red[2][0] + red[2][1] + red[2][2] + red[2][3];
        float d = tn > 1.f ? tn : 1.f;
        out_scalars[0] = tv / d;
        out_scalars[1] = tc / d;
    }
}

extern "C" void kernel_launch(void* const* d_in, const int* in_sizes, int n_in,
                              void* d_out, int out_size, void* d_ws, size_t ws_size,
                              hipStream_t stream) {
    const float* feat  = (const float*)d_in[0];
    const float* radii = (const float*)d_in[1];
    const float* w1rc  = (const float*)d_in[2];
    const float* b1rc  = (const float*)d_in[3];
    const float* w2rc  = (const float*)d_in[4];
    const float* b2rc  = (const float*)d_in[5];
    const float* w3rc  = (const float*)d_in[6];
    const float* b3rc  = (const float*)d_in[7];
    const float* w1cp  = (const float*)d_in[8];
    const float* b1cp  = (const float*)d_in[9];
    const float* w2cp  = (const float*)d_in[10];
    const float* b2cp  = (const float*)d_in[11];
    const int*   eidx  = (const int*)d_in[12];
    const int*   types = (const int*)d_in[13];

    int n = in_sizes[0] / F;          // 300000
    int m = in_sizes[12] / 2;         // 3000000

    int nblocks = (n + BLK_NODES - 1) / BLK_NODES;
    int np = nblocks * 4;
    int nbins = (n + BIN_SIZE - 1) >> BIN_SHIFT;

    // ws layout: wt1t | wt2t | min1 | min2 | partials | gates | counts | offsets | cursors | region(binned/featbf overlay)
    char* ws = (char*)d_ws;
    short* wt1t = (short*)ws;                            ws += 128 * 192 * 2;
    short* wt2t = (short*)ws;                            ws += 48 * 128 * 2;
    int* min1 = (int*)ws;                                ws += (size_t)n * 4;
    int* min2 = (int*)ws;                                ws += (size_t)n * 4;
    float4* partials = (float4*)ws;                      ws += (size_t)np * 16;
    float* gates = (float*)ws;                           ws += (size_t)n * 4;
    int* counts  = (int*)ws;                             ws += NBIN_PAD * 4;
    int* offsets = (int*)ws;                             ws += (NBIN_PAD + 4) * 4;   // 16B-align keep
    int* cursors = (int*)ws;                             ws += NBIN_PAD * 4;

    size_t used = (size_t)(ws - (char*)d_ws);
    size_t binned_bytes = (size_t)2 * m * 4;
    size_t featbf_bytes = (size_t)n * F * 2;
    unsigned* binned = (unsigned*)ws;
    short* featbf = (short*)ws;
    bool useBinned = (n < (1 << 19)) && (nbins <= NBIN_PAD) && (used + binned_bytes <= ws_size);
    bool useBF = (used + featbf_bytes) <= ws_size;

    float* out         = (float*)d_out;
    float* out_scalars = out + (size_t)n * F;

    int bs = 256;
    const int* e0 = eidx;
    const int* e1 = eidx + m;

    // -------- edge phase --------
    if (useBinned) {
        zero_counts<<<1, NBIN_PAD, 0, stream>>>(counts);
        count_kernel<<<1024, bs, 0, stream>>>(e0, e1, counts, m);
        scan_kernel<<<1, NBIN_PAD, 0, stream>>>(counts, offsets, cursors);
        scatter_kernel<<<768, bs, 0, stream>>>(e0, e1, cursors, binned, m);
        process_kernel<<<nbins, bs, 0, stream>>>(binned, offsets, min1, min2, n);
    } else {
        int mt4 = (m + 3) / 4;
        init_min12<<<(n + bs - 1) / bs, bs, 0, stream>>>(min1, min2, n);
        edge_min1_kernel<<<(mt4 + bs - 1) / bs, bs, 0, stream>>>(e0, e1, min1, m);
        edge_min2_kernel<<<(mt4 + bs - 1) / bs, bs, 0, stream>>>(e0, e1, min1, min2, m);
    }

    // -------- prep (featbf overlays binned; runs after edge phase) --------
    prep_w1<<<dim3(128, 3), 64, 0, stream>>>(w1rc, w1cp, wt1t);
    prep_w2<<<dim3(48, 2), 64, 0, stream>>>(w2rc, w2cp, wt2t);
    if (useBF) {
        long total = (long)n * F;
        long nthr = total / 8;
        prep_feat<<<(unsigned)((nthr + bs - 1) / bs), bs, 0, stream>>>(feat, featbf, total);
    }

    // -------- node + update + finalize --------
    if (useBF) {
        node_kernel<true><<<nblocks, bs, 0, stream>>>(
            feat, featbf, radii, b1rc, b2rc, w3rc, b3rc, b1cp, b2cp,
            wt1t, wt2t, types, min1, min2, gates, partials, n);
    } else {
        node_kernel<false><<<nblocks, bs, 0, stream>>>(
            feat, featbf, radii, b1rc, b2rc, w3rc, b3rc, b1cp, b2cp,
            wt1t, wt2t, types, min1, min2, gates, partials, n);
    }
    long total4 = (long)n * F / 4;
    update_kernel<<<2048, bs, 0, stream>>>(feat, gates, out, total4);
    finalize_kernel<<<1, 256, 0, stream>>>(partials, np, out_scalars);
}

// Round 12
// 306.421 us; speedup vs baseline: 2.1861x; 1.0323x over previous
//
#include <hip/hip_runtime.h>
#include <math.h>

#define F 64
#define VIOL_THRESH 0.2f
#define BLK_NODES 128
#define H_ROWB 272   // 136 bf16 per row: 68 words ≡ 4 mod 32 banks -> 2-way (free)
#define BIN_SHIFT 11
#define BIN_SIZE 2048
#define NBIN_PAD 256
#define TILE 2048

typedef float  f32x4  __attribute__((ext_vector_type(4)));
typedef short  bf16x8 __attribute__((ext_vector_type(8)));

__device__ __forceinline__ short f2bf(float f) {
    unsigned u = __builtin_bit_cast(unsigned, f);
    unsigned r = (u + 0x7fffu + ((u >> 16) & 1u)) >> 16;
    return (short)r;
}

// ---------------- fused setup: zero counts/delta + weight transposes ----------------
__global__ __launch_bounds__(256)
void setup_kernel(int* __restrict__ counts, int* __restrict__ delta,
                  const float* __restrict__ w1rc, const float* __restrict__ w1cp,
                  short* __restrict__ wt1t,
                  const float* __restrict__ w2rc, const float* __restrict__ w2cp,
                  short* __restrict__ wt2t) {
    int b = blockIdx.x, tid = threadIdx.x;
    if (b == 0) { counts[tid] = 0; delta[tid] = 0; return; }
    b -= 1;
    if (b < 24) {                      // wt2t: 48*128 = 6144 elems
        int e = b * 256 + tid;
        int o = e >> 7, k = e & 127;
        float v = 0.f;
        if (o < 32)       { if (k < 64) v = w2rc[k * 32 + o]; }
        else if (o == 32) { if (k >= 64) v = w2cp[k - 64]; }
        int kp = (k & 15) * 8 + (k >> 4);
        wt2t[o * 128 + kp] = f2bf(v);
        return;
    }
    b -= 24;
    {                                  // wt1t: 128*192 = 24576 elems
        int e = b * 256 + tid;
        int o = e / 192, k = e % 192;
        const float* src = (o < 64) ? (w1rc + o) : (w1cp + (o - 64));
        wt1t[o * 192 + k] = f2bf(src[(size_t)k * 64]);
    }
}

// ---------------- binned two-smallest-neighbor pipeline ----------------
__global__ __launch_bounds__(256)
void count_kernel(const int* __restrict__ e0, const int* __restrict__ e1,
                  int* __restrict__ counts, int m) {
    __shared__ int c[NBIN_PAD];
    int tid = threadIdx.x;
    c[tid] = 0;
    __syncthreads();
    for (long j = (long)blockIdx.x * 256 + tid; j < m; j += (long)gridDim.x * 256) {
        int u = e0[j], v = e1[j];
        if (u != v) {
            atomicAdd(&c[u >> BIN_SHIFT], 1);
            atomicAdd(&c[v >> BIN_SHIFT], 1);
        }
    }
    __syncthreads();
    if (c[tid]) atomicAdd(&counts[tid], c[tid]);
}

__global__ __launch_bounds__(256)
void scatter_kernel(const int* __restrict__ e0, const int* __restrict__ e1,
                    const int* __restrict__ counts, int* __restrict__ delta,
                    unsigned* __restrict__ binned, int m) {
    __shared__ unsigned long long buf[2 * TILE];          // 32 KB
    __shared__ int goff[NBIN_PAD];
    __shared__ int tcount[NBIN_PAD], toff[NBIN_PAD], tmp[NBIN_PAD];
    __shared__ int gbase[NBIN_PAD], tcur[NBIN_PAD];
    __shared__ int totalsh;
    int tid = threadIdx.x;

    // in-block exclusive scan of global counts -> bin base offsets
    int c = counts[tid];
    tmp[tid] = c;
    __syncthreads();
    for (int off = 1; off < NBIN_PAD; off <<= 1) {
        int v = (tid >= off) ? tmp[tid - off] : 0;
        __syncthreads();
        tmp[tid] += v;
        __syncthreads();
    }
    goff[tid] = tmp[tid] - c;
    __syncthreads();

    int ntile = (m + TILE - 1) / TILE;
    for (int tile = blockIdx.x; tile < ntile; tile += gridDim.x) {
        int base = tile * TILE;
        int lim = min(TILE, m - base);
        tcount[tid] = 0;
        __syncthreads();
        for (int j = tid; j < lim; j += 256) {
            int u = e0[base + j], v = e1[base + j];
            if (u != v) {
                atomicAdd(&tcount[u >> BIN_SHIFT], 1);
                atomicAdd(&tcount[v >> BIN_SHIFT], 1);
            }
        }
        __syncthreads();
        tmp[tid] = tcount[tid];
        __syncthreads();
        for (int off = 1; off < NBIN_PAD; off <<= 1) {
            int vv = (tid >= off) ? tmp[tid - off] : 0;
            __syncthreads();
            tmp[tid] += vv;
            __syncthreads();
        }
        toff[tid] = tmp[tid] - tcount[tid];
        if (tid == NBIN_PAD - 1) totalsh = tmp[NBIN_PAD - 1];
        {
            int cct = tcount[tid];
            gbase[tid] = goff[tid] + (cct ? atomicAdd(&delta[tid], cct) : 0);
            tcur[tid] = tmp[tid] - cct;
        }
        __syncthreads();
        for (int j = tid; j < lim; j += 256) {
            int u = e0[base + j], v = e1[base + j];
            if (u != v) {
                int b1 = u >> BIN_SHIFT;
                int s1 = atomicAdd(&tcur[b1], 1);
                buf[s1] = ((unsigned long long)b1 << 32) |
                          (unsigned)(((u & (BIN_SIZE - 1)) << 19) | v);
                int b2 = v >> BIN_SHIFT;
                int s2 = atomicAdd(&tcur[b2], 1);
                buf[s2] = ((unsigned long long)b2 << 32) |
                          (unsigned)(((v & (BIN_SIZE - 1)) << 19) | u);
            }
        }
        __syncthreads();
        int total = totalsh;
        for (int t = tid; t < total; t += 256) {
            unsigned long long e = buf[t];
            int b = (int)(e >> 32);
            binned[gbase[b] + (t - toff[b])] = (unsigned)e;
        }
        __syncthreads();
    }
}

__global__ __launch_bounds__(256)
void process_kernel(const unsigned* __restrict__ binned, const int* __restrict__ counts,
                    int* __restrict__ min1, int* __restrict__ min2, int n) {
    __shared__ int m1s[BIN_SIZE], m2s[BIN_SIZE];   // 16 KB
    __shared__ int tmp[NBIN_PAD];
    __shared__ int s_sh, e_sh;
    int tid = threadIdx.x, b = blockIdx.x;
    int c = counts[tid];
    tmp[tid] = c;
    __syncthreads();
    for (int off = 1; off < NBIN_PAD; off <<= 1) {
        int v = (tid >= off) ? tmp[tid - off] : 0;
        __syncthreads();
        tmp[tid] += v;
        __syncthreads();
    }
    if (tid == b) { e_sh = tmp[tid]; s_sh = tmp[tid] - c; }
    for (int i = tid; i < BIN_SIZE; i += 256) { m1s[i] = n; m2s[i] = n; }
    __syncthreads();
    int s = s_sh, e = e_sh;
    for (int j = s + tid; j < e; j += 256) {
        unsigned p = binned[j];
        atomicMin(&m1s[p >> 19], (int)(p & 0x7FFFFu));
    }
    __syncthreads();
    for (int j = s + tid; j < e; j += 256) {
        unsigned p = binned[j];
        int lu = p >> 19, v = (int)(p & 0x7FFFFu);
        if (v != m1s[lu]) atomicMin(&m2s[lu], v);
    }
    __syncthreads();
    int gb = b << BIN_SHIFT;
    for (int i = tid; i < BIN_SIZE; i += 256) {
        int g = gb + i;
        if (g < n) { min1[g] = m1s[i]; min2[g] = m2s[i]; }
    }
}

// ---------------- device-scope fallback (n too large or ws too small) ----------------
__global__ void init_min12(int* __restrict__ min1, int* __restrict__ min2, int n) {
    int i = blockIdx.x * blockDim.x + threadIdx.x;
    if (i < n) { min1[i] = n; min2[i] = n; }
}

__device__ __forceinline__ void upd_min1(int u, int v, int* __restrict__ min1) {
    if (u != v) {
        if (v < min1[u]) atomicMin(&min1[u], v);
        if (u < min1[v]) atomicMin(&min1[v], u);
    }
}

__global__ void edge_min1_kernel(const int* __restrict__ e0, const int* __restrict__ e1,
                                 int* __restrict__ min1, int m) {
    int t = blockIdx.x * blockDim.x + threadIdx.x;
    int base = t * 4;
    if (base >= m) return;
    if (base + 4 <= m) {
        int4 u4 = *(const int4*)(e0 + base);
        int4 v4 = *(const int4*)(e1 + base);
        upd_min1(u4.x, v4.x, min1);
        upd_min1(u4.y, v4.y, min1);
        upd_min1(u4.z, v4.z, min1);
        upd_min1(u4.w, v4.w, min1);
    } else {
        for (int j = base; j < m; j++) upd_min1(e0[j], e1[j], min1);
    }
}

__device__ __forceinline__ void upd_min2(int u, int v, const int* __restrict__ min1,
                                         int* __restrict__ min2) {
    if (u != v) {
        if (v != min1[u] && v < min2[u]) atomicMin(&min2[u], v);
        if (u != min1[v] && u < min2[v]) atomicMin(&min2[v], u);
    }
}

__global__ void edge_min2_kernel(const int* __restrict__ e0, const int* __restrict__ e1,
                                 const int* __restrict__ min1, int* __restrict__ min2, int m) {
    int t = blockIdx.x * blockDim.x + threadIdx.x;
    int base = t * 4;
    if (base >= m) return;
    if (base + 4 <= m) {
        int4 u4 = *(const int4*)(e0 + base);
        int4 v4 = *(const int4*)(e1 + base);
        upd_min2(u4.x, v4.x, min1, min2);
        upd_min2(u4.y, v4.y, min1, min2);
        upd_min2(u4.z, v4.z, min1, min2);
        upd_min2(u4.w, v4.w, min1, min2);
    } else {
        for (int j = base; j < m; j++) upd_min2(e0[j], e1[j], min1, min2);
    }
}

// ---------------- feature bf16 prep ----------------
__global__ void prep_feat(const float* __restrict__ f, short* __restrict__ fb, long total) {
    long t = (long)blockIdx.x * blockDim.x + threadIdx.x;
    long base = t * 8;
    if (base >= total) return;
    float4 a = *(const float4*)(f + base);
    float4 b = *(const float4*)(f + base + 4);
    bf16x8 o;
    o[0] = f2bf(a.x); o[1] = f2bf(a.y); o[2] = f2bf(a.z); o[3] = f2bf(a.w);
    o[4] = f2bf(b.x); o[5] = f2bf(b.y); o[6] = f2bf(b.z); o[7] = f2bf(b.w);
    *(bf16x8*)(fb + base) = o;
}

// ---------------- fused node + feature-update kernel ----------------
template<bool BF>
__global__ __launch_bounds__(256)
void node_kernel(const float* __restrict__ feat, const short* __restrict__ featbf,
                 const float* __restrict__ radii,
                 const float* __restrict__ b1rc, const float* __restrict__ b2rc,
                 const float* __restrict__ w3rc, const float* __restrict__ b3rc,
                 const float* __restrict__ b1cp, const float* __restrict__ b2cp,
                 const short* __restrict__ wt1t, const short* __restrict__ wt2t,
                 const int* __restrict__ types,
                 const int* __restrict__ min1, const int* __restrict__ min2,
                 float* __restrict__ out, float4* __restrict__ partials,
                 int n) {
    // No __syncthreads: each wave touches ONLY its own 32-node slice of LDS.
    __shared__ __align__(16) char Hbuf[BLK_NODES * H_ROWB];
    __shared__ float corrArr[BLK_NODES];
    __shared__ float zArr[BLK_NODES];
    __shared__ float gateArr[BLK_NODES];

    int tid = threadIdx.x;
    int blk = blockIdx.x;
    int lane = tid & 63;
    int w = tid >> 6;
    int lm = lane & 15;
    int lg = lane >> 4;
    int wnb = w * 32;

    int nid[2][3];
#pragma unroll
    for (int mt = 0; mt < 2; mt++) {
        int g = blk * BLK_NODES + wnb + mt * 16 + lm;
        int ii = (g < n) ? g : (n - 1);
        int m1 = min1[ii];
        int m2 = min2[ii];
        nid[mt][0] = ii;
        nid[mt][1] = (m1 < n) ? m1 : (n - 1);
        nid[mt][2] = (m2 < n) ? m2 : (n - 1);
    }

    bf16x8 af[2][3][2];
    if constexpr (BF) {
#pragma unroll
        for (int mt = 0; mt < 2; mt++)
#pragma unroll
            for (int part = 0; part < 3; part++)
#pragma unroll
                for (int h = 0; h < 2; h++)
                    af[mt][part][h] = *(const bf16x8*)(featbf + (size_t)nid[mt][part] * F + h * 32 + lg * 8);
    }

    f32x4 zero4 = {0.f, 0.f, 0.f, 0.f};
    f32x4 acc[2][8];
#pragma unroll
    for (int mt = 0; mt < 2; mt++)
#pragma unroll
        for (int nt = 0; nt < 8; nt++) acc[mt][nt] = zero4;

#pragma unroll
    for (int s = 0; s < 6; s++) {
        int part = s >> 1;
        int h = s & 1;
        bf16x8 a0, a1;
        if constexpr (BF) {
            a0 = af[0][part][h];
            a1 = af[1][part][h];
        } else {
#pragma unroll
            for (int mt = 0; mt < 2; mt++) {
                const float* rp = feat + (size_t)nid[mt][part] * F + h * 32 + lg * 8;
                float4 f0 = *(const float4*)rp;
                float4 f1 = *(const float4*)(rp + 4);
                bf16x8 a;
                a[0] = f2bf(f0.x); a[1] = f2bf(f0.y); a[2] = f2bf(f0.z); a[3] = f2bf(f0.w);
                a[4] = f2bf(f1.x); a[5] = f2bf(f1.y); a[6] = f2bf(f1.z); a[7] = f2bf(f1.w);
                if (mt == 0) a0 = a; else a1 = a;
            }
        }
#pragma unroll
        for (int nt = 0; nt < 8; nt++) {
            bf16x8 b = *(const bf16x8*)(wt1t + (lm + 16 * nt) * 192 + s * 32 + lg * 8);
            acc[0][nt] = __builtin_amdgcn_mfma_f32_16x16x32_bf16(a0, b, acc[0][nt], 0, 0, 0);
            acc[1][nt] = __builtin_amdgcn_mfma_f32_16x16x32_bf16(a1, b, acc[1][nt], 0, 0, 0);
        }
    }

    float b1v[8];
#pragma unroll
    for (int nt = 0; nt < 8; nt++)
        b1v[nt] = (nt < 4) ? b1rc[lm + 16 * nt] : b1cp[lm + 16 * nt - 64];

#pragma unroll
    for (int mt = 0; mt < 2; mt++) {
#pragma unroll
        for (int r = 0; r < 4; r++) {
            int node = wnb + mt * 16 + lg * 4 + r;
            bf16x8 hv;
#pragma unroll
            for (int nt = 0; nt < 8; nt++)
                hv[nt] = f2bf(fmaxf(acc[mt][nt][r] + b1v[nt], 0.f));
            *(bf16x8*)(Hbuf + node * H_ROWB + lm * 16) = hv;
        }
    }

    f32x4 acc2[2][3];
#pragma unroll
    for (int mt = 0; mt < 2; mt++)
#pragma unroll
        for (int nt = 0; nt < 3; nt++) acc2[mt][nt] = zero4;

#pragma unroll
    for (int s = 0; s < 4; s++) {
        bf16x8 af2[2];
#pragma unroll
        for (int mt = 0; mt < 2; mt++)
            af2[mt] = *(const bf16x8*)(Hbuf + (wnb + mt * 16 + lm) * H_ROWB + s * 64 + lg * 16);
#pragma unroll
        for (int nt = 0; nt < 3; nt++) {
            bf16x8 b = *(const bf16x8*)(wt2t + (lm + 16 * nt) * 128 + s * 32 + lg * 8);
            acc2[0][nt] = __builtin_amdgcn_mfma_f32_16x16x32_bf16(af2[0], b, acc2[0][nt], 0, 0, 0);
            acc2[1][nt] = __builtin_amdgcn_mfma_f32_16x16x32_bf16(af2[1], b, acc2[1][nt], 0, 0, 0);
        }
    }

#pragma unroll
    for (int mt = 0; mt < 2; mt++) {
#pragma unroll
        for (int r = 0; r < 4; r++) {
            float t = 0.f;
#pragma unroll
            for (int nt = 0; nt < 2; nt++) {
                int o = lm + 16 * nt;
                float s2v = fmaxf(acc2[mt][nt][r] + b2rc[o], 0.f);
                t = fmaf(s2v, w3rc[o], t);
            }
            float zz = acc2[mt][2][r];
#pragma unroll
            for (int msk = 1; msk < 16; msk <<= 1) {
                t  += __shfl_xor(t, msk);
                zz += __shfl_xor(zz, msk);
            }
            if (lm == 0) {
                int node = wnb + mt * 16 + lg * 4 + r;
                corrArr[node] = t + b3rc[0];
                zArr[node]    = zz + b2cp[0];
            }
        }
    }

    // ---------- per-wave epilogue ----------
    float sv = 0.f, sc = 0.f, ct = 0.f;
    if (lane < 32) {
        int loc = wnb + lane;
        int g = blk * BLK_NODES + loc;
        bool live = g < n;
        int ii = live ? g : (n - 1);
        int m1 = min1[ii];
        int m2 = min2[ii];
        bool valid = m2 < n;
        int c1 = (m1 < n) ? m1 : (n - 1);
        int c2 = (m2 < n) ? m2 : (n - 1);
        float rp_ = radii[ii], r1_ = radii[c1], r2_ = radii[c2];
        float pr3 = rp_ * rp_ * rp_;
        float viol = fabsf(r1_ * r1_ * r1_ + r2_ * r2_ * r2_ - pr3) / pr3;
        bool active = live && valid && (types[ii] == 1);
        bool upd = active && (viol > VIOL_THRESH);
        float gate = upd ? corrArr[loc] : 0.f;
        gateArr[loc] = 0.1f * gate;
        if (active) {
            sv = viol;
            sc = 1.0f / (1.0f + expf(-zArr[loc]));
            ct = 1.f;
        }
    }
#pragma unroll
    for (int off = 32; off > 0; off >>= 1) {
        sv += __shfl_down(sv, off);
        sc += __shfl_down(sc, off);
        ct += __shfl_down(ct, off);
    }
    if (lane == 0) {
        float4 p; p.x = sv; p.y = sc; p.z = ct; p.w = 0.f;
        partials[blk * 4 + w] = p;
    }

    // ---------- fused feature update: wave streams its own contiguous 8 KB ----------
    {
        size_t wbase = (size_t)(blk * BLK_NODES + wnb) * F;
        const float* fsrc = feat + wbase;
        float* fdst = out + wbase;
#pragma unroll
        for (int q = 0; q < 8; q++) {
            int elem = q * 256 + lane * 4;
            int nloc = wnb + (elem >> 6);
            int g = blk * BLK_NODES + nloc;
            if (g < n) {
                float gate01 = gateArr[nloc];
                float4 v = *(const float4*)(fsrc + elem);
                float4 r;
                r.x = v.x + gate01 * tanhf(v.x);
                r.y = v.y + gate01 * tanhf(v.y);
                r.z = v.z + gate01 * tanhf(v.z);
                r.w = v.w + gate01 * tanhf(v.w);
                *(float4*)(fdst + elem) = r;
            }
        }
    }
}

__global__ __launch_bounds__(256)
void finalize_kernel(const float4* __restrict__ partials, int np,
                     float* __restrict__ out_scalars) {
    __shared__ float red[3][4];
    int tid = threadIdx.x;
    float sv = 0.f, sc = 0.f, ct = 0.f;
    for (int i = tid; i < np; i += 256) {
        float4 p = partials[i];
        sv += p.x; sc += p.y; ct += p.z;
    }
#pragma unroll
    for (int off = 32; off > 0; off >>= 1) {
        sv += __shfl_down(sv, off);
        sc += __shfl_down(sc, off);
        ct += __shfl_down(ct, off);
    }
    int lane = tid & 63, w = tid >> 6;
    if (lane == 0) { red[0][w] = sv; red[1][w] = sc; red[2][w] = ct; }
    __syncthreads();
    if (tid == 0) {
        float tv = red[0][0] + red[0][1] + red[0][2] + red[0][3];
        float tc = red[1][0] + red[1][1] + red[1][2] + red[1][3];
        float tn = red[2][0] + red[2][1] + red[2][2] + red[2][3];
        float d = tn > 1.f ? tn : 1.f;
        out_scalars[0] = tv / d;
        out_scalars[1] = tc / d;
    }
}

extern "C" void kernel_launch(void* const* d_in, const int* in_sizes, int n_in,
                              void* d_out, int out_size, void* d_ws, size_t ws_size,
                              hipStream_t stream) {
    const float* feat  = (const float*)d_in[0];
    const float* radii = (const float*)d_in[1];
    const float* w1rc  = (const float*)d_in[2];
    const float* b1rc  = (const float*)d_in[3];
    const float* w2rc  = (const float*)d_in[4];
    const float* b2rc  = (const float*)d_in[5];
    const float* w3rc  = (const float*)d_in[6];
    const float* b3rc  = (const float*)d_in[7];
    const float* w1cp  = (const float*)d_in[8];
    const float* b1cp  = (const float*)d_in[9];
    const float* w2cp  = (const float*)d_in[10];
    const float* b2cp  = (const float*)d_in[11];
    const int*   eidx  = (const int*)d_in[12];
    const int*   types = (const int*)d_in[13];

    int n = in_sizes[0] / F;          // 300000
    int m = in_sizes[12] / 2;         // 3000000

    int nblocks = (n + BLK_NODES - 1) / BLK_NODES;
    int np = nblocks * 4;
    int nbins = (n + BIN_SIZE - 1) >> BIN_SHIFT;

    // ws layout: wt1t | wt2t | min1 | min2 | partials | counts | delta | region(binned/featbf overlay)
    char* ws = (char*)d_ws;
    short* wt1t = (short*)ws;                            ws += 128 * 192 * 2;
    short* wt2t = (short*)ws;                            ws += 48 * 128 * 2;
    int* min1 = (int*)ws;                                ws += (size_t)n * 4;
    int* min2 = (int*)ws;                                ws += (size_t)n * 4;
    float4* partials = (float4*)ws;                      ws += (size_t)np * 16;
    int* counts = (int*)ws;                              ws += NBIN_PAD * 4;
    int* delta  = (int*)ws;                              ws += NBIN_PAD * 4;

    size_t used = (size_t)(ws - (char*)d_ws);
    size_t binned_bytes = (size_t)2 * m * 4;
    size_t featbf_bytes = (size_t)n * F * 2;
    unsigned* binned = (unsigned*)ws;
    short* featbf = (short*)ws;
    bool useBinned = (n < (1 << 19)) && (nbins <= NBIN_PAD) && (used + binned_bytes <= ws_size);
    bool useBF = (used + featbf_bytes) <= ws_size;

    float* out         = (float*)d_out;
    float* out_scalars = out + (size_t)n * F;

    int bs = 256;
    const int* e0 = eidx;
    const int* e1 = eidx + m;

    // -------- setup (zero counts/delta + weight transposes): 1 + 24 + 96 blocks --------
    setup_kernel<<<121, bs, 0, stream>>>(counts, delta, w1rc, w1cp, wt1t, w2rc, w2cp, wt2t);

    // -------- edge phase --------
    if (useBinned) {
        count_kernel<<<1024, bs, 0, stream>>>(e0, e1, counts, m);
        scatter_kernel<<<768, bs, 0, stream>>>(e0, e1, counts, delta, binned, m);
        process_kernel<<<nbins, bs, 0, stream>>>(binned, counts, min1, min2, n);
    } else {
        int mt4 = (m + 3) / 4;
        init_min12<<<(n + bs - 1) / bs, bs, 0, stream>>>(min1, min2, n);
        edge_min1_kernel<<<(mt4 + bs - 1) / bs, bs, 0, stream>>>(e0, e1, min1, m);
        edge_min2_kernel<<<(mt4 + bs - 1) / bs, bs, 0, stream>>>(e0, e1, min1, min2, m);
    }

    // -------- feature bf16 prep (featbf overlays binned; runs after edge phase) --------
    if (useBF) {
        long total = (long)n * F;
        long nthr = total / 8;
        prep_feat<<<(unsigned)((nthr + bs - 1) / bs), bs, 0, stream>>>(feat, featbf, total);
    }

    // -------- fused node + update --------
    if (useBF) {
        node_kernel<true><<<nblocks, bs, 0, stream>>>(
            feat, featbf, radii, b1rc, b2rc, w3rc, b3rc, b1cp, b2cp,
            wt1t, wt2t, types, min1, min2, out, partials, n);
    } else {
        node_kernel<false><<<nblocks, bs, 0, stream>>>(
            feat, featbf, radii, b1rc, b2rc, w3rc, b3rc, b1cp, b2cp,
            wt1t, wt2t, types, min1, min2, out, partials, n);
    }
    finalize_kernel<<<1, 256, 0, stream>>>(partials, np, out_scalars);
}

// Round 13
// 301.858 us; speedup vs baseline: 2.2192x; 1.0151x over previous
//
#include <hip/hip_runtime.h>
#include <math.h>

#define F 64
#define VIOL_THRESH 0.2f
#define BLK_NODES 128
#define H_ROWB 272   // 136 bf16 per row: 68 words ≡ 4 mod 32 banks -> 2-way (free)
#define BIN_SHIFT 11
#define BIN_SIZE 2048
#define NBIN_PAD 256
#define TILE 2048

typedef float  f32x4  __attribute__((ext_vector_type(4)));
typedef short  bf16x8 __attribute__((ext_vector_type(8)));

__device__ __forceinline__ short f2bf(float f) {
    unsigned u = __builtin_bit_cast(unsigned, f);
    unsigned r = (u + 0x7fffu + ((u >> 16) & 1u)) >> 16;
    return (short)r;
}

__device__ __forceinline__ float fexp2(float x) {
#if __has_builtin(__builtin_amdgcn_exp2f)
    return __builtin_amdgcn_exp2f(x);
#else
    return exp2f(x);
#endif
}

__device__ __forceinline__ float frcp(float x) {
#if __has_builtin(__builtin_amdgcn_rcpf)
    return __builtin_amdgcn_rcpf(x);
#else
    return 1.0f / x;
#endif
}

// tanh(x) = (e^{2x}-1)/(e^{2x}+1), e^{2x}=2^{2x*log2(e)}; clamp avoids inf/inf
__device__ __forceinline__ float fast_tanh(float x) {
    float xc = fminf(fmaxf(x, -9.0f), 9.0f);
    float e = fexp2(xc * 2.885390081777927f);
    return (e - 1.0f) * frcp(e + 1.0f);
}

__device__ __forceinline__ float fast_sigmoid(float z) {
    return frcp(1.0f + fexp2(-z * 1.4426950408889634f));
}

// ---------------- fused setup: zero counts/delta + weight transposes ----------------
__global__ __launch_bounds__(256)
void setup_kernel(int* __restrict__ counts, int* __restrict__ delta,
                  const float* __restrict__ w1rc, const float* __restrict__ w1cp,
                  short* __restrict__ wt1t,
                  const float* __restrict__ w2rc, const float* __restrict__ w2cp,
                  short* __restrict__ wt2t) {
    int b = blockIdx.x, tid = threadIdx.x;
    if (b == 0) { counts[tid] = 0; delta[tid] = 0; return; }
    b -= 1;
    if (b < 24) {                      // wt2t: 48*128 = 6144 elems
        int e = b * 256 + tid;
        int o = e >> 7, k = e & 127;
        float v = 0.f;
        if (o < 32)       { if (k < 64) v = w2rc[k * 32 + o]; }
        else if (o == 32) { if (k >= 64) v = w2cp[k - 64]; }
        int kp = (k & 15) * 8 + (k >> 4);
        wt2t[o * 128 + kp] = f2bf(v);
        return;
    }
    b -= 24;
    {                                  // wt1t: 128*192 = 24576 elems
        int e = b * 256 + tid;
        int o = e / 192, k = e % 192;
        const float* src = (o < 64) ? (w1rc + o) : (w1cp + (o - 64));
        wt1t[o * 192 + k] = f2bf(src[(size_t)k * 64]);
    }
}

// ---------------- count histogram (+ optional fused feature bf16 prep) ----------------
__global__ __launch_bounds__(256)
void count_prep_kernel(const int* __restrict__ e0, const int* __restrict__ e1,
                       int* __restrict__ counts, int m,
                       const float* __restrict__ feat, short* __restrict__ featbf,
                       long total, int cblocks) {
    int tid = threadIdx.x;
    if ((int)blockIdx.x < cblocks) {
        __shared__ int c[NBIN_PAD];
        c[tid] = 0;
        __syncthreads();
        for (long j = (long)blockIdx.x * 256 + tid; j < m; j += (long)cblocks * 256) {
            int u = e0[j], v = e1[j];
            if (u != v) {
                atomicAdd(&c[u >> BIN_SHIFT], 1);
                atomicAdd(&c[v >> BIN_SHIFT], 1);
            }
        }
        __syncthreads();
        if (c[tid]) atomicAdd(&counts[tid], c[tid]);
    } else {
        long t = (long)((int)blockIdx.x - cblocks) * 256 + tid;
        long base = t * 8;
        if (base >= total) return;
        float4 a = *(const float4*)(feat + base);
        float4 b = *(const float4*)(feat + base + 4);
        bf16x8 o;
        o[0] = f2bf(a.x); o[1] = f2bf(a.y); o[2] = f2bf(a.z); o[3] = f2bf(a.w);
        o[4] = f2bf(b.x); o[5] = f2bf(b.y); o[6] = f2bf(b.z); o[7] = f2bf(b.w);
        *(bf16x8*)(featbf + base) = o;
    }
}

__global__ __launch_bounds__(256)
void scatter_kernel(const int* __restrict__ e0, const int* __restrict__ e1,
                    const int* __restrict__ counts, int* __restrict__ delta,
                    unsigned* __restrict__ binned, int m) {
    __shared__ unsigned long long buf[2 * TILE];          // 32 KB
    __shared__ int goff[NBIN_PAD];
    __shared__ int tcount[NBIN_PAD], toff[NBIN_PAD], tmp[NBIN_PAD];
    __shared__ int gbase[NBIN_PAD], tcur[NBIN_PAD];
    __shared__ int totalsh;
    int tid = threadIdx.x;

    int c = counts[tid];
    tmp[tid] = c;
    __syncthreads();
    for (int off = 1; off < NBIN_PAD; off <<= 1) {
        int v = (tid >= off) ? tmp[tid - off] : 0;
        __syncthreads();
        tmp[tid] += v;
        __syncthreads();
    }
    goff[tid] = tmp[tid] - c;
    __syncthreads();

    int ntile = (m + TILE - 1) / TILE;
    for (int tile = blockIdx.x; tile < ntile; tile += gridDim.x) {
        int base = tile * TILE;
        int lim = min(TILE, m - base);
        tcount[tid] = 0;
        __syncthreads();
        for (int j = tid; j < lim; j += 256) {
            int u = e0[base + j], v = e1[base + j];
            if (u != v) {
                atomicAdd(&tcount[u >> BIN_SHIFT], 1);
                atomicAdd(&tcount[v >> BIN_SHIFT], 1);
            }
        }
        __syncthreads();
        tmp[tid] = tcount[tid];
        __syncthreads();
        for (int off = 1; off < NBIN_PAD; off <<= 1) {
            int vv = (tid >= off) ? tmp[tid - off] : 0;
            __syncthreads();
            tmp[tid] += vv;
            __syncthreads();
        }
        toff[tid] = tmp[tid] - tcount[tid];
        if (tid == NBIN_PAD - 1) totalsh = tmp[NBIN_PAD - 1];
        {
            int cct = tcount[tid];
            gbase[tid] = goff[tid] + (cct ? atomicAdd(&delta[tid], cct) : 0);
            tcur[tid] = tmp[tid] - cct;
        }
        __syncthreads();
        for (int j = tid; j < lim; j += 256) {
            int u = e0[base + j], v = e1[base + j];
            if (u != v) {
                int b1 = u >> BIN_SHIFT;
                int s1 = atomicAdd(&tcur[b1], 1);
                buf[s1] = ((unsigned long long)b1 << 32) |
                          (unsigned)(((u & (BIN_SIZE - 1)) << 19) | v);
                int b2 = v >> BIN_SHIFT;
                int s2 = atomicAdd(&tcur[b2], 1);
                buf[s2] = ((unsigned long long)b2 << 32) |
                          (unsigned)(((v & (BIN_SIZE - 1)) << 19) | u);
            }
        }
        __syncthreads();
        int total = totalsh;
        for (int t = tid; t < total; t += 256) {
            unsigned long long e = buf[t];
            int b = (int)(e >> 32);
            binned[gbase[b] + (t - toff[b])] = (unsigned)e;
        }
        __syncthreads();
    }
}

__global__ __launch_bounds__(256)
void process_kernel(const unsigned* __restrict__ binned, const int* __restrict__ counts,
                    int* __restrict__ min1, int* __restrict__ min2, int n) {
    __shared__ int m1s[BIN_SIZE], m2s[BIN_SIZE];   // 16 KB
    __shared__ int tmp[NBIN_PAD];
    __shared__ int s_sh, e_sh;
    int tid = threadIdx.x, b = blockIdx.x;
    int c = counts[tid];
    tmp[tid] = c;
    __syncthreads();
    for (int off = 1; off < NBIN_PAD; off <<= 1) {
        int v = (tid >= off) ? tmp[tid - off] : 0;
        __syncthreads();
        tmp[tid] += v;
        __syncthreads();
    }
    if (tid == b) { e_sh = tmp[tid]; s_sh = tmp[tid] - c; }
    for (int i = tid; i < BIN_SIZE; i += 256) { m1s[i] = n; m2s[i] = n; }
    __syncthreads();
    int s = s_sh, e = e_sh;
    for (int j = s + tid; j < e; j += 256) {
        unsigned p = binned[j];
        atomicMin(&m1s[p >> 19], (int)(p & 0x7FFFFu));
    }
    __syncthreads();
    for (int j = s + tid; j < e; j += 256) {
        unsigned p = binned[j];
        int lu = p >> 19, v = (int)(p & 0x7FFFFu);
        if (v != m1s[lu]) atomicMin(&m2s[lu], v);
    }
    __syncthreads();
    int gb = b << BIN_SHIFT;
    for (int i = tid; i < BIN_SIZE; i += 256) {
        int g = gb + i;
        if (g < n) { min1[g] = m1s[i]; min2[g] = m2s[i]; }
    }
}

// ---------------- device-scope fallback ----------------
__global__ void init_min12(int* __restrict__ min1, int* __restrict__ min2, int n) {
    int i = blockIdx.x * blockDim.x + threadIdx.x;
    if (i < n) { min1[i] = n; min2[i] = n; }
}

__device__ __forceinline__ void upd_min1(int u, int v, int* __restrict__ min1) {
    if (u != v) {
        if (v < min1[u]) atomicMin(&min1[u], v);
        if (u < min1[v]) atomicMin(&min1[v], u);
    }
}

__global__ void edge_min1_kernel(const int* __restrict__ e0, const int* __restrict__ e1,
                                 int* __restrict__ min1, int m) {
    int t = blockIdx.x * blockDim.x + threadIdx.x;
    int base = t * 4;
    if (base >= m) return;
    if (base + 4 <= m) {
        int4 u4 = *(const int4*)(e0 + base);
        int4 v4 = *(const int4*)(e1 + base);
        upd_min1(u4.x, v4.x, min1);
        upd_min1(u4.y, v4.y, min1);
        upd_min1(u4.z, v4.z, min1);
        upd_min1(u4.w, v4.w, min1);
    } else {
        for (int j = base; j < m; j++) upd_min1(e0[j], e1[j], min1);
    }
}

__device__ __forceinline__ void upd_min2(int u, int v, const int* __restrict__ min1,
                                         int* __restrict__ min2) {
    if (u != v) {
        if (v != min1[u] && v < min2[u]) atomicMin(&min2[u], v);
        if (u != min1[v] && u < min2[v]) atomicMin(&min2[v], u);
    }
}

__global__ void edge_min2_kernel(const int* __restrict__ e0, const int* __restrict__ e1,
                                 const int* __restrict__ min1, int* __restrict__ min2, int m) {
    int t = blockIdx.x * blockDim.x + threadIdx.x;
    int base = t * 4;
    if (base >= m) return;
    if (base + 4 <= m) {
        int4 u4 = *(const int4*)(e0 + base);
        int4 v4 = *(const int4*)(e1 + base);
        upd_min2(u4.x, v4.x, min1, min2);
        upd_min2(u4.y, v4.y, min1, min2);
        upd_min2(u4.z, v4.z, min1, min2);
        upd_min2(u4.w, v4.w, min1, min2);
    } else {
        for (int j = base; j < m; j++) upd_min2(e0[j], e1[j], min1, min2);
    }
}

// ---------------- standalone feature bf16 prep (overlay / fallback paths) ----------------
__global__ void prep_feat(const float* __restrict__ f, short* __restrict__ fb, long total) {
    long t = (long)blockIdx.x * blockDim.x + threadIdx.x;
    long base = t * 8;
    if (base >= total) return;
    float4 a = *(const float4*)(f + base);
    float4 b = *(const float4*)(f + base + 4);
    bf16x8 o;
    o[0] = f2bf(a.x); o[1] = f2bf(a.y); o[2] = f2bf(a.z); o[3] = f2bf(a.w);
    o[4] = f2bf(b.x); o[5] = f2bf(b.y); o[6] = f2bf(b.z); o[7] = f2bf(b.w);
    *(bf16x8*)(fb + base) = o;
}

// ---------------- fused node + feature-update kernel ----------------
template<bool BF>
__global__ __launch_bounds__(256)
void node_kernel(const float* __restrict__ feat, const short* __restrict__ featbf,
                 const float* __restrict__ radii,
                 const float* __restrict__ b1rc, const float* __restrict__ b2rc,
                 const float* __restrict__ w3rc, const float* __restrict__ b3rc,
                 const float* __restrict__ b1cp, const float* __restrict__ b2cp,
                 const short* __restrict__ wt1t, const short* __restrict__ wt2t,
                 const int* __restrict__ types,
                 const int* __restrict__ min1, const int* __restrict__ min2,
                 float* __restrict__ out, float4* __restrict__ partials,
                 int n) {
    // No __syncthreads: each wave touches ONLY its own 32-node slice of LDS.
    __shared__ __align__(16) char Hbuf[BLK_NODES * H_ROWB];
    __shared__ float corrArr[BLK_NODES];
    __shared__ float zArr[BLK_NODES];
    __shared__ float gateArr[BLK_NODES];

    int tid = threadIdx.x;
    int blk = blockIdx.x;
    int lane = tid & 63;
    int w = tid >> 6;
    int lm = lane & 15;
    int lg = lane >> 4;
    int wnb = w * 32;

    int nid[2][3];
#pragma unroll
    for (int mt = 0; mt < 2; mt++) {
        int g = blk * BLK_NODES + wnb + mt * 16 + lm;
        int ii = (g < n) ? g : (n - 1);
        int m1 = min1[ii];
        int m2 = min2[ii];
        nid[mt][0] = ii;
        nid[mt][1] = (m1 < n) ? m1 : (n - 1);
        nid[mt][2] = (m2 < n) ? m2 : (n - 1);
    }

    // ---- early epilogue prefetch (all lanes load; lanes 32-63 mirror 0-31) ----
    int el = lane & 31;
    int eg = blk * BLK_NODES + wnb + el;
    bool elive = eg < n;
    int eii = elive ? eg : (n - 1);
    int em1 = min1[eii];
    int em2 = min2[eii];
    float er0 = radii[eii];
    int ety = types[eii];
    int ec1 = (em1 < n) ? em1 : (n - 1);
    int ec2 = (em2 < n) ? em2 : (n - 1);
    float er1 = radii[ec1];
    float er2 = radii[ec2];

    bf16x8 af[2][3][2];
    if constexpr (BF) {
#pragma unroll
        for (int mt = 0; mt < 2; mt++)
#pragma unroll
            for (int part = 0; part < 3; part++)
#pragma unroll
                for (int h = 0; h < 2; h++)
                    af[mt][part][h] = *(const bf16x8*)(featbf + (size_t)nid[mt][part] * F + h * 32 + lg * 8);
    }

    f32x4 zero4 = {0.f, 0.f, 0.f, 0.f};
    f32x4 acc[2][8];
#pragma unroll
    for (int mt = 0; mt < 2; mt++)
#pragma unroll
        for (int nt = 0; nt < 8; nt++) acc[mt][nt] = zero4;

#pragma unroll
    for (int s = 0; s < 6; s++) {
        int part = s >> 1;
        int h = s & 1;
        bf16x8 a0, a1;
        if constexpr (BF) {
            a0 = af[0][part][h];
            a1 = af[1][part][h];
        } else {
#pragma unroll
            for (int mt = 0; mt < 2; mt++) {
                const float* rp = feat + (size_t)nid[mt][part] * F + h * 32 + lg * 8;
                float4 f0 = *(const float4*)rp;
                float4 f1 = *(const float4*)(rp + 4);
                bf16x8 a;
                a[0] = f2bf(f0.x); a[1] = f2bf(f0.y); a[2] = f2bf(f0.z); a[3] = f2bf(f0.w);
                a[4] = f2bf(f1.x); a[5] = f2bf(f1.y); a[6] = f2bf(f1.z); a[7] = f2bf(f1.w);
                if (mt == 0) a0 = a; else a1 = a;
            }
        }
#pragma unroll
        for (int nt = 0; nt < 8; nt++) {
            bf16x8 b = *(const bf16x8*)(wt1t + (lm + 16 * nt) * 192 + s * 32 + lg * 8);
            acc[0][nt] = __builtin_amdgcn_mfma_f32_16x16x32_bf16(a0, b, acc[0][nt], 0, 0, 0);
            acc[1][nt] = __builtin_amdgcn_mfma_f32_16x16x32_bf16(a1, b, acc[1][nt], 0, 0, 0);
        }
    }

    float b1v[8];
#pragma unroll
    for (int nt = 0; nt < 8; nt++)
        b1v[nt] = (nt < 4) ? b1rc[lm + 16 * nt] : b1cp[lm + 16 * nt - 64];

#pragma unroll
    for (int mt = 0; mt < 2; mt++) {
#pragma unroll
        for (int r = 0; r < 4; r++) {
            int node = wnb + mt * 16 + lg * 4 + r;
            bf16x8 hv;
#pragma unroll
            for (int nt = 0; nt < 8; nt++)
                hv[nt] = f2bf(fmaxf(acc[mt][nt][r] + b1v[nt], 0.f));
            *(bf16x8*)(Hbuf + node * H_ROWB + lm * 16) = hv;
        }
    }

    f32x4 acc2[2][3];
#pragma unroll
    for (int mt = 0; mt < 2; mt++)
#pragma unroll
        for (int nt = 0; nt < 3; nt++) acc2[mt][nt] = zero4;

#pragma unroll
    for (int s = 0; s < 4; s++) {
        bf16x8 af2[2];
#pragma unroll
        for (int mt = 0; mt < 2; mt++)
            af2[mt] = *(const bf16x8*)(Hbuf + (wnb + mt * 16 + lm) * H_ROWB + s * 64 + lg * 16);
#pragma unroll
        for (int nt = 0; nt < 3; nt++) {
            bf16x8 b = *(const bf16x8*)(wt2t + (lm + 16 * nt) * 128 + s * 32 + lg * 8);
            acc2[0][nt] = __builtin_amdgcn_mfma_f32_16x16x32_bf16(af2[0], b, acc2[0][nt], 0, 0, 0);
            acc2[1][nt] = __builtin_amdgcn_mfma_f32_16x16x32_bf16(af2[1], b, acc2[1][nt], 0, 0, 0);
        }
    }

#pragma unroll
    for (int mt = 0; mt < 2; mt++) {
#pragma unroll
        for (int r = 0; r < 4; r++) {
            float t = 0.f;
#pragma unroll
            for (int nt = 0; nt < 2; nt++) {
                int o = lm + 16 * nt;
                float s2v = fmaxf(acc2[mt][nt][r] + b2rc[o], 0.f);
                t = fmaf(s2v, w3rc[o], t);
            }
            float zz = acc2[mt][2][r];
#pragma unroll
            for (int msk = 1; msk < 16; msk <<= 1) {
                t  += __shfl_xor(t, msk);
                zz += __shfl_xor(zz, msk);
            }
            if (lm == 0) {
                int node = wnb + mt * 16 + lg * 4 + r;
                corrArr[node] = t + b3rc[0];
                zArr[node]    = zz + b2cp[0];
            }
        }
    }

    // ---------- per-wave epilogue (uses prefetched values) ----------
    float sv = 0.f, sc = 0.f, ct = 0.f;
    if (lane < 32) {
        bool valid = em2 < n;
        float pr3 = er0 * er0 * er0;
        float viol = fabsf(er1 * er1 * er1 + er2 * er2 * er2 - pr3) / pr3;
        bool active = elive && valid && (ety == 1);
        bool upd = active && (viol > VIOL_THRESH);
        float gate = upd ? corrArr[wnb + el] : 0.f;
        gateArr[wnb + el] = 0.1f * gate;
        if (active) {
            sv = viol;
            sc = fast_sigmoid(zArr[wnb + el]);
            ct = 1.f;
        }
    }
#pragma unroll
    for (int off = 32; off > 0; off >>= 1) {
        sv += __shfl_down(sv, off);
        sc += __shfl_down(sc, off);
        ct += __shfl_down(ct, off);
    }
    if (lane == 0) {
        float4 p; p.x = sv; p.y = sc; p.z = ct; p.w = 0.f;
        partials[blk * 4 + w] = p;
    }

    // ---------- fused feature update: wave streams its own contiguous 8 KB ----------
    {
        size_t wbase = (size_t)(blk * BLK_NODES + wnb) * F;
        const float* fsrc = feat + wbase;
        float* fdst = out + wbase;
#pragma unroll
        for (int q = 0; q < 8; q++) {
            int elem = q * 256 + lane * 4;
            int nloc = wnb + (elem >> 6);
            int g = blk * BLK_NODES + nloc;
            if (g < n) {
                float gate01 = gateArr[nloc];
                float4 v = *(const float4*)(fsrc + elem);
                float4 r;
                r.x = v.x + gate01 * fast_tanh(v.x);
                r.y = v.y + gate01 * fast_tanh(v.y);
                r.z = v.z + gate01 * fast_tanh(v.z);
                r.w = v.w + gate01 * fast_tanh(v.w);
                *(float4*)(fdst + elem) = r;
            }
        }
    }
}

__global__ __launch_bounds__(256)
void finalize_kernel(const float4* __restrict__ partials, int np,
                     float* __restrict__ out_scalars) {
    __shared__ float red[3][4];
    int tid = threadIdx.x;
    float sv = 0.f, sc = 0.f, ct = 0.f;
    for (int i = tid; i < np; i += 256) {
        float4 p = partials[i];
        sv += p.x; sc += p.y; ct += p.z;
    }
#pragma unroll
    for (int off = 32; off > 0; off >>= 1) {
        sv += __shfl_down(sv, off);
        sc += __shfl_down(sc, off);
        ct += __shfl_down(ct, off);
    }
    int lane = tid & 63, w = tid >> 6;
    if (lane == 0) { red[0][w] = sv; red[1][w] = sc; red[2][w] = ct; }
    __syncthreads();
    if (tid == 0) {
        float tv = red[0][0] + red[0][1] + red[0][2] + red[0][3];
        float tc = red[1][0] + red[1][1] + red[1][2] + red[1][3];
        float tn = red[2][0] + red[2][1] + red[2][2] + red[2][3];
        float d = tn > 1.f ? tn : 1.f;
        out_scalars[0] = tv / d;
        out_scalars[1] = tc / d;
    }
}

extern "C" void kernel_launch(void* const* d_in, const int* in_sizes, int n_in,
                              void* d_out, int out_size, void* d_ws, size_t ws_size,
                              hipStream_t stream) {
    const float* feat  = (const float*)d_in[0];
    const float* radii = (const float*)d_in[1];
    const float* w1rc  = (const float*)d_in[2];
    const float* b1rc  = (const float*)d_in[3];
    const float* w2rc  = (const float*)d_in[4];
    const float* b2rc  = (const float*)d_in[5];
    const float* w3rc  = (const float*)d_in[6];
    const float* b3rc  = (const float*)d_in[7];
    const float* w1cp  = (const float*)d_in[8];
    const float* b1cp  = (const float*)d_in[9];
    const float* w2cp  = (const float*)d_in[10];
    const float* b2cp  = (const float*)d_in[11];
    const int*   eidx  = (const int*)d_in[12];
    const int*   types = (const int*)d_in[13];

    int n = in_sizes[0] / F;          // 300000
    int m = in_sizes[12] / 2;         // 3000000

    int nblocks = (n + BLK_NODES - 1) / BLK_NODES;
    int np = nblocks * 4;
    int nbins = (n + BIN_SIZE - 1) >> BIN_SHIFT;

    // ws layout: wt1t | wt2t | min1 | min2 | partials | counts | delta | [binned][featbf]
    char* ws = (char*)d_ws;
    short* wt1t = (short*)ws;                            ws += 128 * 192 * 2;
    short* wt2t = (short*)ws;                            ws += 48 * 128 * 2;
    int* min1 = (int*)ws;                                ws += (size_t)n * 4;
    int* min2 = (int*)ws;                                ws += (size_t)n * 4;
    float4* partials = (float4*)ws;                      ws += (size_t)np * 16;
    int* counts = (int*)ws;                              ws += NBIN_PAD * 4;
    int* delta  = (int*)ws;                              ws += NBIN_PAD * 4;

    size_t used = (size_t)(ws - (char*)d_ws);
    size_t binned_bytes = (size_t)2 * m * 4;
    size_t featbf_bytes = (size_t)n * F * 2;

    bool useBinned = (n < (1 << 19)) && (nbins <= NBIN_PAD) && (used + binned_bytes <= ws_size);
    bool sepBuf    = useBinned && (used + binned_bytes + featbf_bytes <= ws_size);
    unsigned* binned = (unsigned*)ws;
    short* featbf;
    bool useBF;
    if (sepBuf) {
        featbf = (short*)(ws + binned_bytes);
        useBF = true;
    } else {
        featbf = (short*)ws;   // overlays binned (sequential use)
        useBF = (used + featbf_bytes) <= ws_size;
    }

    float* out         = (float*)d_out;
    float* out_scalars = out + (size_t)n * F;

    int bs = 256;
    const int* e0 = eidx;
    const int* e1 = eidx + m;
    long total = (long)n * F;
    long prepthr = total / 8;
    int prepblocks = (int)((prepthr + bs - 1) / bs);

    // -------- setup (zero counts/delta + weight transposes) --------
    setup_kernel<<<121, bs, 0, stream>>>(counts, delta, w1rc, w1cp, wt1t, w2rc, w2cp, wt2t);

    // -------- edge phase --------
    if (useBinned) {
        if (sepBuf && useBF) {
            // count + feature-prep fused (independent streams, disjoint buffers)
            count_prep_kernel<<<1024 + prepblocks, bs, 0, stream>>>(
                e0, e1, counts, m, feat, featbf, total, 1024);
        } else {
            count_prep_kernel<<<1024, bs, 0, stream>>>(
                e0, e1, counts, m, feat, featbf, 0, 1024);
        }
        scatter_kernel<<<768, bs, 0, stream>>>(e0, e1, counts, delta, binned, m);
        process_kernel<<<nbins, bs, 0, stream>>>(binned, counts, min1, min2, n);
        if (!sepBuf && useBF)   // overlay: prep only after binned fully consumed
            prep_feat<<<prepblocks, bs, 0, stream>>>(feat, featbf, total);
    } else {
        int mt4 = (m + 3) / 4;
        init_min12<<<(n + bs - 1) / bs, bs, 0, stream>>>(min1, min2, n);
        edge_min1_kernel<<<(mt4 + bs - 1) / bs, bs, 0, stream>>>(e0, e1, min1, m);
        edge_min2_kernel<<<(mt4 + bs - 1) / bs, bs, 0, stream>>>(e0, e1, min1, min2, m);
        if (useBF)
            prep_feat<<<prepblocks, bs, 0, stream>>>(feat, featbf, total);
    }

    // -------- fused node + update --------
    if (useBF) {
        node_kernel<true><<<nblocks, bs, 0, stream>>>(
            feat, featbf, radii, b1rc, b2rc, w3rc, b3rc, b1cp, b2cp,
            wt1t, wt2t, types, min1, min2, out, partials, n);
    } else {
        node_kernel<false><<<nblocks, bs, 0, stream>>>(
            feat, featbf, radii, b1rc, b2rc, w3rc, b3rc, b1cp, b2cp,
            wt1t, wt2t, types, min1, min2, out, partials, n);
    }
    finalize_kernel<<<1, 256, 0, stream>>>(partials, np, out_scalars);
}